// Round 4
// baseline (5370.407 us; speedup 1.0000x reference)
//
#include <hip/hip_runtime.h>

// ---------------------------------------------------------------------------
// Bidirectional 2-layer GRU (B=256, L=200, IN=512, H=256) + FC heads.
// R10: R9 hidden-split design with the exchange-buffer placement bug fixed.
//   R9 FAILED because flags0/mbox0 overlapped wcat0 (live GEMM weights):
//   gemm block(0,0) zeroed 256 B of w_z row 512 while other blocks read it.
//   Fix: mbox0/flags0 -> outh region (dead until gru1 overwrites it; gemm0
//   reads only xh/wcat0/bcat0 so its flag-zeroing touches nothing live).
//        mbox1/flags1 -> xh region (dead after gemm0; gemm1 reads l0/wcat1).
//   Design (R9): grid dim3(16,2,2) = 64 CUs; block (bt,dir,hf) owns h cols
//   [hf*128,hf*128+128); all 3 gate weights pinned in 96 VGPRs (zero weight
//   LDS traffic); per-step 4 KB h-half exchange with partner (id^32) via
//   agent-scope atomics at LLC, release/acquire flag; exchange hidden under
//   own-half-K MFMAs. R6 cx<-nx fence pattern preserved (R7 lesson).
// ---------------------------------------------------------------------------

typedef _Float16 half8 __attribute__((ext_vector_type(8)));
typedef _Float16 half4v __attribute__((ext_vector_type(4)));
typedef float fx4 __attribute__((ext_vector_type(4)));

#define BATCH 256
#define SEQ   200
#define HID   256
#define MROWS (BATCH*SEQ)   // 51200
#define NG    1536          // 3H * 2 directions
#define KDIM  512

__device__ __forceinline__ void gload_lds16(const _Float16* g, _Float16* l) {
  __builtin_amdgcn_global_load_lds((const __attribute__((address_space(1))) void*)g,
                                   (__attribute__((address_space(3))) void*)l, 16, 0, 0);
}

// Barrier that drains only LDS ops (lgkmcnt), NOT vmcnt: global stores/loads
// stay outstanding across the barrier.
__device__ __forceinline__ void gru_barrier() {
  asm volatile("s_waitcnt lgkmcnt(0)\n\ts_barrier" ::: "memory");
}

// ---------------------------- prep kernels ---------------------------------

__global__ __launch_bounds__(256) void k_cast_x(const float4* __restrict__ x,
                                                half4v* __restrict__ xh, int n4) {
  int i = blockIdx.x * 256 + threadIdx.x;
  if (i < n4) {
    float4 v = x[i];
    half4v o;
    o[0] = (_Float16)v.x; o[1] = (_Float16)v.y; o[2] = (_Float16)v.z; o[3] = (_Float16)v.w;
    xh[i] = o;
  }
}

// Concat input-projection weights [1536][512] fp16; bias = bih + (bhh for r,z only)
__global__ __launch_bounds__(256) void k_prep_wih(const float* __restrict__ wf,
                                                  const float* __restrict__ wr,
                                                  const float* __restrict__ bf_,
                                                  const float* __restrict__ br_,
                                                  const float* __restrict__ bhf,
                                                  const float* __restrict__ bhr,
                                                  _Float16* __restrict__ wcat,
                                                  float* __restrict__ bcat) {
  int idx = blockIdx.x * 256 + threadIdx.x;     // < 1536*512
  int n = idx >> 9;
  float v = (n < 768) ? wf[idx] : wr[idx - 768 * 512];
  wcat[idx] = (_Float16)v;
  if (idx < 1536) {
    float b;
    if (idx < 768) b = bf_[idx] + ((idx < 512) ? bhf[idx] : 0.f);
    else { int i2 = idx - 768; b = br_[i2] + ((i2 < 512) ? bhr[i2] : 0.f); }
    bcat[idx] = b;
  }
}

// Pack w_hh into MFMA B-fragment order: [dir][T(16)][gate(3)][kf(8)][lane(64)][i(8)]
__global__ __launch_bounds__(256) void k_prep_whh(const float* __restrict__ whf,
                                                  const float* __restrict__ whr,
                                                  _Float16* __restrict__ whp) {
  int e = blockIdx.x * 256 + threadIdx.x;       // < 2*196608
  int dir = e / 196608;
  int r = e - dir * 196608;
  int w = r / 12288;  int r2 = r - w * 12288;
  int gate = r2 >> 12; int r3 = r2 & 4095;
  int kf = r3 >> 9;    int r4 = r3 & 511;
  int lane = r4 >> 3;  int i = r4 & 7;
  int row = gate * 256 + w * 16 + (lane & 15);
  int col = kf * 32 + (lane >> 4) * 8 + i;
  const float* src = dir ? whr : whf;
  whp[e] = (_Float16)src[row * 256 + col];
}

// ---------------------------- xi GEMM (m97 structure) ----------------------
// XCD-aware remap (R7): the 12 N-blocks sharing an A-tile run consecutively
// on one XCD. Also zeroes the gru flag array for the FOLLOWING gru dispatch
// (graph-replay-safe reset). flags MUST NOT overlap anything this gemm reads
// (R9 bug: flags inside wcat corrupted live weights).
__global__ __launch_bounds__(256) void k_gemm(const _Float16* __restrict__ A,
                                              const _Float16* __restrict__ Wt,
                                              const float* __restrict__ bias,
                                              _Float16* __restrict__ C,
                                              unsigned* __restrict__ flags) {
  __shared__ __align__(16) _Float16 As[128 * 32];
  __shared__ __align__(16) _Float16 Bs[128 * 32];
  const int tid = threadIdx.x;
  if (blockIdx.x == 0 && blockIdx.y == 0 && tid < 64) flags[tid] = 0u;

  const int wv = tid >> 6, ln = tid & 63;
  const int wm = wv >> 1, wn = wv & 1;
  const int jl = ln & 15, q = ln >> 4;

  const int lid  = blockIdx.x + 400 * blockIdx.y;   // dispatch order
  const int xcd  = lid & 7;
  const int slot = lid >> 3;                        // 0..599
  const int mi   = xcd * 50 + (slot / 12);          // 0..399
  const int ni   = slot % 12;                       // 0..11
  const int m0 = mi * 128, n0 = ni * 128;

  const int r0 = tid >> 2, k80 = (tid & 3) * 8;
  const int r1 = r0 + 64;

  fx4 acc[4][4];
#pragma unroll
  for (int a = 0; a < 4; ++a)
#pragma unroll
    for (int b = 0; b < 4; ++b) acc[a][b] = (fx4){0.f, 0.f, 0.f, 0.f};

  for (int kk = 0; kk < KDIM; kk += 32) {
    gload_lds16(A  + (size_t)(m0 + r0) * KDIM + kk + k80, As + tid * 8);
    gload_lds16(A  + (size_t)(m0 + r1) * KDIM + kk + k80, As + (tid + 256) * 8);
    gload_lds16(Wt + (size_t)(n0 + r0) * KDIM + kk + k80, Bs + tid * 8);
    gload_lds16(Wt + (size_t)(n0 + r1) * KDIM + kk + k80, Bs + (tid + 256) * 8);
    __syncthreads();
    half8 af[4], bfr[4];
#pragma unroll
    for (int mt = 0; mt < 4; ++mt)
      af[mt] = *(const half8*)(As + (wm * 64 + mt * 16 + jl) * 32 + q * 8);
#pragma unroll
    for (int nt = 0; nt < 4; ++nt)
      bfr[nt] = *(const half8*)(Bs + (wn * 64 + nt * 16 + jl) * 32 + q * 8);
#pragma unroll
    for (int mt = 0; mt < 4; ++mt)
#pragma unroll
      for (int nt = 0; nt < 4; ++nt)
        acc[mt][nt] = __builtin_amdgcn_mfma_f32_16x16x32_f16(af[mt], bfr[nt], acc[mt][nt], 0, 0, 0);
    __syncthreads();
  }

  float bsv[4];
#pragma unroll
  for (int nt = 0; nt < 4; ++nt) bsv[nt] = bias[n0 + wn * 64 + nt * 16 + jl];

  for (int mt = 0; mt < 4; ++mt) {
#pragma unroll
    for (int nt = 0; nt < 4; ++nt)
#pragma unroll
      for (int rg = 0; rg < 4; ++rg)
        As[(wm * 16 + q * 4 + rg) * 128 + wn * 64 + nt * 16 + jl] =
            (_Float16)(acc[mt][nt][rg] + bsv[nt]);
    __syncthreads();
#pragma unroll
    for (int i = 0; i < 2; ++i) {
      int idx = i * 256 + tid;
      int rl = idx >> 4, c8 = idx & 15;
      int grow = m0 + (rl >> 4) * 64 + mt * 16 + (rl & 15);
      *(half8*)(C + (size_t)grow * NG + n0 + c8 * 8) = *(const half8*)(As + rl * 128 + c8 * 8);
    }
    __syncthreads();
  }
}

// ---------------------------- GRU recurrence -------------------------------
// 64 blocks (16 batch-tiles x 2 dirs x 2 hidden-halves) x 512 threads.
// Block (bt,dir,hf) computes h cols [hf*128, hf*128+128) for 16 batch rows.
// Wave w owns 16 cols (tile T = hf*8+w); all 3 gate weights pinned in VGPRs.
// LDS: hs[parity][half][16][128] fp16, chunk-XOR swizzle (c ^= row).
// Per-step partner exchange: 8 B/thread through agent-scope atomics (LLC),
// release/acquire flag per block. All 64 blocks co-resident -> no deadlock.
__global__ __launch_bounds__(512) __attribute__((amdgpu_waves_per_eu(2, 2)))
void k_gru(const _Float16* __restrict__ xi,
           const _Float16* __restrict__ whp,
           const float* __restrict__ bhhf,
           const float* __restrict__ bhhr,
           _Float16* __restrict__ out,
           unsigned* __restrict__ flags,    // [64]
           unsigned* __restrict__ mbox) {   // [64][2][1024] u32
  __shared__ __align__(16) _Float16 hs[8192];   // 16 KB

  const int tid = threadIdx.x, w = tid >> 6, ln = tid & 63;
  const int jl = ln & 15, q = ln >> 4;
  const int bt = blockIdx.x, dir = blockIdx.y, hf = blockIdx.z;
  const float* bhh = dir ? bhhr : bhhf;

  const int fid = bt + 16 * dir + 32 * hf;
  unsigned* myflag = flags + fid;
  unsigned* pflag  = flags + (fid ^ 32);
  unsigned* mb_me  = mbox + (size_t)fid * 2048;
  unsigned* mb_pr  = mbox + (size_t)(fid ^ 32) * 2048;

  // ---- all 3 gate weights pinned in VGPR (tile T = hf*8 + w) ----
  half8 wgt[3][8];
  const _Float16* wb = whp + ((size_t)(dir * 16 + hf * 8 + w)) * 12288;
#pragma unroll
  for (int g = 0; g < 3; ++g)
#pragma unroll
    for (int kf = 0; kf < 8; ++kf) {
      wgt[g][kf] = *(const half8*)(wb + g * 4096 + kf * 512 + ln * 8);
      asm volatile("" : "+v"(wgt[g][kf]));   // pin: opaque def, no remat
    }
  const float bhn = bhh[512 + hf * 128 + w * 16 + jl];

  for (int i = tid; i < 4096; i += 512) hs[i] = (_Float16)0.f;  // parity 0 = h(-1)=0

  // ---- xi pointers + preload t0 ----
  const long long t0 = dir ? (SEQ - 1) : 0;
  const int xstep = dir ? -NG : NG;
  const int wcol = hf * 128 + w * 16 + jl;
  const _Float16* xp[4];
#pragma unroll
  for (int rg = 0; rg < 4; ++rg)
    xp[rg] = xi + ((size_t)((bt * 16 + q * 4 + rg) * SEQ) + t0) * NG + dir * 768;

  _Float16 cx[3][4];
#pragma unroll
  for (int rg = 0; rg < 4; ++rg)
#pragma unroll
    for (int g = 0; g < 3; ++g)
      cx[g][rg] = xp[rg][g * 256 + wcol];

  // ---- own-half out-store (threads 0..255): 16 rows x 16 col-chunks ----
  const int orow = (tid & 255) >> 4, occ = tid & 15;
  _Float16* op = out + ((size_t)((bt * 16 + orow) * SEQ) + t0) * 512
               + dir * 256 + hf * 128 + occ * 8;
  const int ostep = dir ? -512 : 512;
  const int oaddr = hf * 2048 + orow * 128 + ((occ ^ orow) << 3);

  // epilogue write coords: local col and chunk
  const int ec = (w * 16 + jl) >> 3;   // chunk 0..15 (= w*2 + (jl>>3))
  const int ew = jl & 7;               // within-chunk element

  float hprev[4] = {0.f, 0.f, 0.f, 0.f};
  __syncthreads();   // h(-1) zeroed

  for (int t = 0; t < SEQ; ++t) {
    const int p = t & 1;
    _Float16* hb  = hs + p * 4096;          // holds h(t-1)
    _Float16* hbw = hs + (p ^ 1) * 4096;    // receives h(t)

    // ---- sync with partner; fetch its h(t-1) (8 B/thread via LLC) ----
    unsigned m0v = 0, m1v = 0;
    if (t > 0) {
      while (__hip_atomic_load(pflag, __ATOMIC_ACQUIRE,
                               __HIP_MEMORY_SCOPE_AGENT) < (unsigned)t) {}
      const unsigned* src = mb_pr + (size_t)((t - 1) & 1) * 1024 + tid * 2;
      m0v = __hip_atomic_load(src,     __ATOMIC_RELAXED, __HIP_MEMORY_SCOPE_AGENT);
      m1v = __hip_atomic_load(src + 1, __ATOMIC_RELAXED, __HIP_MEMORY_SCOPE_AGENT);
    }

    // xi(t+1) prefetch into regs (R6 pattern: consumed by copies at step end)
    _Float16 nx[3][4];
    if (t < SEQ - 1) {
#pragma unroll
      for (int rg = 0; rg < 4; ++rg) {
        const _Float16* pp = xp[rg] + xstep;
#pragma unroll
        for (int g = 0; g < 3; ++g) nx[g][rg] = pp[g * 256 + wcol];
      }
    }

    fx4 acc[3];
    acc[0] = (fx4){0.f, 0.f, 0.f, 0.f};
    acc[1] = (fx4){0.f, 0.f, 0.f, 0.f};
    acc[2] = (fx4){bhn, bhn, bhn, bhn};

    // own-half h(t-1) -> global (own region stable since last barrier)
    if (t > 0 && tid < 256) { *(half8*)op = *(const half8*)(hb + oaddr); op += ostep; }

    // ---- own-half-K MFMAs (kf = hf*4 .. hf*4+3); hides LLC latency ----
#pragma unroll
    for (int kk = 0; kk < 4; ++kk) {
      const int kf = hf * 4 + kk;
      const int cc = kf * 4 + q;
      const int hsel = cc >> 4, lc = cc & 15;
      half8 a = *(const half8*)(hb + hsel * 2048 + jl * 128 + ((lc ^ jl) << 3));
      acc[0] = __builtin_amdgcn_mfma_f32_16x16x32_f16(a, wgt[0][kf], acc[0], 0, 0, 0);
      acc[1] = __builtin_amdgcn_mfma_f32_16x16x32_f16(a, wgt[1][kf], acc[1], 0, 0, 0);
      acc[2] = __builtin_amdgcn_mfma_f32_16x16x32_f16(a, wgt[2][kf], acc[2], 0, 0, 0);
    }
    __builtin_amdgcn_sched_barrier(0);  // keep mailbox-wait after own-K MFMAs

    // ---- land partner half of h(t-1) into LDS ----
    if (t > 0) {
      const unsigned short u0 = (unsigned short)m0v;
      const unsigned short u1 = (unsigned short)(m0v >> 16);
      const unsigned short u2 = (unsigned short)m1v;
      const unsigned short u3 = (unsigned short)(m1v >> 16);
      _Float16* pr = hb + (hf ^ 1) * 2048;
      pr[(q * 4 + 0) * 128 + ((ec ^ (q * 4 + 0)) << 3) + ew] = __builtin_bit_cast(_Float16, u0);
      pr[(q * 4 + 1) * 128 + ((ec ^ (q * 4 + 1)) << 3) + ew] = __builtin_bit_cast(_Float16, u1);
      pr[(q * 4 + 2) * 128 + ((ec ^ (q * 4 + 2)) << 3) + ew] = __builtin_bit_cast(_Float16, u2);
      pr[(q * 4 + 3) * 128 + ((ec ^ (q * 4 + 3)) << 3) + ew] = __builtin_bit_cast(_Float16, u3);
    }
    gru_barrier();   // lgkm-only: partner half visible; vm stays in flight

    // ---- partner-half-K MFMAs ----
#pragma unroll
    for (int kk = 0; kk < 4; ++kk) {
      const int kf = (hf ^ 1) * 4 + kk;
      const int cc = kf * 4 + q;
      const int hsel = cc >> 4, lc = cc & 15;
      half8 a = *(const half8*)(hb + hsel * 2048 + jl * 128 + ((lc ^ jl) << 3));
      acc[0] = __builtin_amdgcn_mfma_f32_16x16x32_f16(a, wgt[0][kf], acc[0], 0, 0, 0);
      acc[1] = __builtin_amdgcn_mfma_f32_16x16x32_f16(a, wgt[1][kf], acc[1], 0, 0, 0);
      acc[2] = __builtin_amdgcn_mfma_f32_16x16x32_f16(a, wgt[2][kf], acc[2], 0, 0, 0);
    }

    // ---- epilogue: gates -> h(t); write own LDS region + mailbox ----
    _Float16 hh[4];
#pragma unroll
    for (int rg = 0; rg < 4; ++rg) {
      const int rr = q * 4 + rg;
      float rv = __builtin_amdgcn_rcpf(1.f + __expf(-(acc[0][rg] + (float)cx[0][rg])));
      float zv = __builtin_amdgcn_rcpf(1.f + __expf(-(acc[1][rg] + (float)cx[1][rg])));
      float gn = fmaf(rv, acc[2][rg], (float)cx[2][rg]);
      float e2 = __expf(2.f * gn);
      float nn = fmaf(-2.f, __builtin_amdgcn_rcpf(e2 + 1.f), 1.f);  // tanh
      float h = fmaf(zv, hprev[rg] - nn, nn);
      hprev[rg] = h;
      hh[rg] = (_Float16)h;
      hbw[hf * 2048 + rr * 128 + ((ec ^ rr) << 3) + ew] = hh[rg];
    }
    {
      unsigned a0 = (unsigned)__builtin_bit_cast(unsigned short, hh[0])
                  | ((unsigned)__builtin_bit_cast(unsigned short, hh[1]) << 16);
      unsigned a1 = (unsigned)__builtin_bit_cast(unsigned short, hh[2])
                  | ((unsigned)__builtin_bit_cast(unsigned short, hh[3]) << 16);
      unsigned* dst = mb_me + (size_t)p * 1024 + tid * 2;
      __hip_atomic_store(dst,     a0, __ATOMIC_RELAXED, __HIP_MEMORY_SCOPE_AGENT);
      __hip_atomic_store(dst + 1, a1, __ATOMIC_RELAXED, __HIP_MEMORY_SCOPE_AGENT);
    }

    // cx <- nx copies (R6 fence placement: forces xi wait here, not earlier)
#pragma unroll
    for (int rg = 0; rg < 4; ++rg) {
      xp[rg] += (t < SEQ - 1) ? xstep : 0;
#pragma unroll
      for (int g = 0; g < 3; ++g) cx[g][rg] = nx[g][rg];
    }

    __syncthreads();   // drains vmcnt(0) (mailbox stores at LLC) + lgkm
    if (tid == 0)
      __hip_atomic_store(myflag, (unsigned)(t + 1), __ATOMIC_RELEASE,
                         __HIP_MEMORY_SCOPE_AGENT);
  }

  // flush own half of h(SEQ-1): epilogue(199) wrote parity 0
  if (tid < 256) *(half8*)op = *(const half8*)(hs + oaddr);
}

// ---------------------------- heads ----------------------------------------

// 3200 blocks x 256 thr; each wave handles 4 (b,t) rows, fc weights cached in
// per-thread registers (cols ln*8..ln*8+7) -> 4x less L2 broadcast traffic.
__global__ __launch_bounds__(256) void k_heads1(const _Float16* __restrict__ out,
                                                const float* __restrict__ fc1w,
                                                const float* __restrict__ fc1b,
                                                const float* __restrict__ fc2w,
                                                const float* __restrict__ fc2b,
                                                float* __restrict__ y,
                                                float* __restrict__ y2) {
  const int tid = threadIdx.x, wv = tid >> 6, ln = tid & 63;

  float4 w1a = *(const float4*)(fc1w + ln * 8);
  float4 w1b = *(const float4*)(fc1w + ln * 8 + 4);
  float4 wa[10], wb[10];
#pragma unroll
  for (int c = 0; c < 10; ++c) {
    wa[c] = *(const float4*)(fc2w + c * 512 + ln * 8);
    wb[c] = *(const float4*)(fc2w + c * 512 + ln * 8 + 4);
  }
  float b1 = fc1b[0];
  float b2[10];
#pragma unroll
  for (int c = 0; c < 10; ++c) b2[c] = fc2b[c];

#pragma unroll
  for (int i = 0; i < 4; ++i) {
    int gw = blockIdx.x * 16 + wv * 4 + i;
    int b = gw / SEQ, t = gw - b * SEQ;
    half8 ov = *(const half8*)(out + (size_t)gw * 512 + ln * 8);
    float o[8];
#pragma unroll
    for (int k = 0; k < 8; ++k) o[k] = (float)ov[k];

    float s1 = o[0]*w1a.x + o[1]*w1a.y + o[2]*w1a.z + o[3]*w1a.w
             + o[4]*w1b.x + o[5]*w1b.y + o[6]*w1b.z + o[7]*w1b.w;
    float s2[10];
#pragma unroll
    for (int c = 0; c < 10; ++c) {
      s2[c] = o[0]*wa[c].x + o[1]*wa[c].y + o[2]*wa[c].z + o[3]*wa[c].w
            + o[4]*wb[c].x + o[5]*wb[c].y + o[6]*wb[c].z + o[7]*wb[c].w;
    }
#pragma unroll
    for (int m = 32; m; m >>= 1) {
      s1 += __shfl_xor(s1, m);
#pragma unroll
      for (int c = 0; c < 10; ++c) s2[c] += __shfl_xor(s2[c], m);
    }
    if (ln == 0) {
      y[gw] = s1 + b1;
      float* y2p = y2 + (size_t)b * 2000 + t * 10;
#pragma unroll
      for (int c = 0; c < 10; ++c) y2p[c] = s2[c] + b2[c];
    }
  }
}

__device__ __forceinline__ float blkRedMax(float v, float* red, int tid) {
#pragma unroll
  for (int m = 32; m; m >>= 1) v = fmaxf(v, __shfl_xor(v, m));
  __syncthreads();
  if ((tid & 63) == 0) red[tid >> 6] = v;
  __syncthreads();
  return fmaxf(fmaxf(red[0], red[1]), fmaxf(red[2], red[3]));
}
__device__ __forceinline__ float blkRedSum(float v, float* red, int tid) {
#pragma unroll
  for (int m = 32; m; m >>= 1) v += __shfl_xor(v, m);
  __syncthreads();
  if ((tid & 63) == 0) red[tid >> 6] = v;
  __syncthreads();
  return red[0] + red[1] + red[2] + red[3];
}

__global__ __launch_bounds__(256) void k_heads2(const float* __restrict__ y,
                                                const float* __restrict__ y2,
                                                float* __restrict__ y3) {
  __shared__ float sp[SEQ];
  __shared__ float se[2000];
  __shared__ float red[4];
  int b = blockIdx.x, tid = threadIdx.x;

  float v = (tid < SEQ) ? y[(size_t)b * SEQ + tid] : -3.0e38f;
  float mx = blkRedMax(v, red, tid);
  float e = (tid < SEQ) ? __expf(v - mx) : 0.f;
  float sum = blkRedSum(e, red, tid);
  if (tid < SEQ) sp[tid] = e / (sum * 10.f);

  float vv[8];
  float lm = -3.0e38f;
#pragma unroll
  for (int r = 0; r < 8; ++r) {
    int k = tid + r * 256;
    vv[r] = (k < 2000) ? y2[(size_t)b * 2000 + k] : -3.0e38f;
    lm = fmaxf(lm, vv[r]);
  }
  float mx2 = blkRedMax(lm, red, tid);
  float ls = 0.f;
#pragma unroll
  for (int r = 0; r < 8; ++r) {
    int k = tid + r * 256;
    if (k < 2000) { float ee = __expf(vv[r] - mx2); se[k] = ee; ls += ee; }
  }
  float sum2 = blkRedSum(ls, red, tid);
  __syncthreads();
  float inv = 1.f / sum2;
#pragma unroll
  for (int r = 0; r < 8; ++r) {
    int k = tid + r * 256;
    if (k < 2000) y3[(size_t)b * 2000 + k] = se[k] * inv + sp[k / 10];
  }
}

// ---------------------------- launch ---------------------------------------

extern "C" void kernel_launch(void* const* d_in, const int* in_sizes, int n_in,
                              void* d_out, int out_size, void* d_ws, size_t ws_size,
                              hipStream_t stream) {
  const float* x     = (const float*)d_in[0];
  const float* wih0  = (const float*)d_in[1];
  const float* whh0  = (const float*)d_in[2];
  const float* bih0  = (const float*)d_in[3];
  const float* bhh0  = (const float*)d_in[4];
  const float* wih0r = (const float*)d_in[5];
  const float* whh0r = (const float*)d_in[6];
  const float* bih0r = (const float*)d_in[7];
  const float* bhh0r = (const float*)d_in[8];
  const float* wih1  = (const float*)d_in[9];
  const float* whh1  = (const float*)d_in[10];
  const float* bih1  = (const float*)d_in[11];
  const float* bhh1  = (const float*)d_in[12];
  const float* wih1r = (const float*)d_in[13];
  const float* whh1r = (const float*)d_in[14];
  const float* bih1r = (const float*)d_in[15];
  const float* bhh1r = (const float*)d_in[16];
  const float* fc1w  = (const float*)d_in[17];
  const float* fc1b  = (const float*)d_in[18];
  const float* fc2w  = (const float*)d_in[19];
  const float* fc2b  = (const float*)d_in[20];

  char* ws = (char*)d_ws;
  _Float16* xh    = (_Float16*)(ws + 0);
  _Float16* xi    = (_Float16*)(ws + 52428800);
  _Float16* l0    = (_Float16*)(ws + 209715200);
  _Float16* outh  = (_Float16*)(ws + 262144000);
  _Float16* wcat0 = (_Float16*)(ws + 314572800);
  _Float16* wcat1 = (_Float16*)(ws + 316145664);
  _Float16* whp0  = (_Float16*)(ws + 317718528);
  _Float16* whp1  = (_Float16*)(ws + 318504960);
  float*    bcat0 = (float*)(ws + 319291392);
  float*    bcat1 = (float*)(ws + 319297536);

  // gru exchange buffers — in memory DEAD at their point of use and never
  // read by the gemm that zeroes the flags (R9 post-mortem):
  //  mbox0/flags0: outh region. gemm0 reads xh/wcat0/bcat0 only -> zeroing
  //    safe; outh dead until gru1 fully overwrites it (after gru0 is done).
  //  mbox1/flags1: xh region. xh dead after gemm0; gemm1 reads l0/wcat1 only.
  unsigned* mbox0  = (unsigned*)(ws + 262144000);            // 512 KB
  unsigned* flags0 = (unsigned*)(ws + 262144000 + 524288);   // 256 B
  unsigned* mbox1  = (unsigned*)(ws + 0);                    // 512 KB
  unsigned* flags1 = (unsigned*)(ws + 524288);               // 256 B

  float* y  = (float*)d_out;
  float* y2 = (float*)d_out + 51200;
  float* y3 = (float*)d_out + 563200;

  k_cast_x<<<25600, 256, 0, stream>>>((const float4*)x, (half4v*)xh, 6553600);
  k_prep_wih<<<3072, 256, 0, stream>>>(wih0, wih0r, bih0, bih0r, bhh0, bhh0r, wcat0, bcat0);
  k_prep_wih<<<3072, 256, 0, stream>>>(wih1, wih1r, bih1, bih1r, bhh1, bhh1r, wcat1, bcat1);
  k_prep_whh<<<1536, 256, 0, stream>>>(whh0, whh0r, whp0);
  k_prep_whh<<<1536, 256, 0, stream>>>(whh1, whh1r, whp1);

  k_gemm<<<dim3(400, 12), 256, 0, stream>>>(xh, wcat0, bcat0, xi, flags0);
  k_gru<<<dim3(16, 2, 2), 512, 0, stream>>>(xi, whp0, bhh0, bhh0r, l0, flags0, mbox0);
  k_gemm<<<dim3(400, 12), 256, 0, stream>>>(l0, wcat1, bcat1, xi, flags1);
  k_gru<<<dim3(16, 2, 2), 512, 0, stream>>>(xi, whp1, bhh1, bhh1r, outh, flags1, mbox1);
  k_heads1<<<3200, 256, 0, stream>>>(outh, fc1w, fc1b, fc2w, fc2b, y, y2);
  k_heads2<<<256, 256, 0, stream>>>(y, y2, y3);
}

// Round 5
// 2464.018 us; speedup vs baseline: 2.1795x; 2.1795x over previous
//
#include <hip/hip_runtime.h>

// ---------------------------------------------------------------------------
// Bidirectional 2-layer GRU (B=256, L=200, IN=512, H=256) + FC heads.
// R11: R8 structure (verified 403us/gru) + ALL THREE gate weight sets pinned
//   in registers (adds n-gate: +16 half8 = 64 regs). nlds deleted entirely:
//   removes 128 loop-invariant ds_read_b128 per CU per step (~1150 cyc of
//   the ~2300-cyc LDS-pipe co-bottleneck). LDS 147KB -> 16KB (h dbuf only).
//   Loop body / cx<-nx fence / lgkm-barrier byte-identical to R8 (R7 lesson:
//   the schedule is fragile; touch nothing else).
//   R9/R10 post-mortem: cross-block per-step sync via agent atomics costs
//   ~25k cyc/step at the coherent point (+150MB HBM traffic) - dead end.
// ---------------------------------------------------------------------------

typedef _Float16 half8 __attribute__((ext_vector_type(8)));
typedef _Float16 half4v __attribute__((ext_vector_type(4)));
typedef float fx4 __attribute__((ext_vector_type(4)));

#define BATCH 256
#define SEQ   200
#define HID   256
#define MROWS (BATCH*SEQ)   // 51200
#define NG    1536          // 3H * 2 directions
#define KDIM  512

__device__ __forceinline__ void gload_lds16(const _Float16* g, _Float16* l) {
  __builtin_amdgcn_global_load_lds((const __attribute__((address_space(1))) void*)g,
                                   (__attribute__((address_space(3))) void*)l, 16, 0, 0);
}

// Barrier that drains only LDS ops (lgkmcnt), NOT vmcnt: global prefetch
// loads stay outstanding across the step boundary.
__device__ __forceinline__ void gru_barrier() {
  asm volatile("s_waitcnt lgkmcnt(0)\n\ts_barrier" ::: "memory");
}

// ---------------------------- prep kernels ---------------------------------

__global__ __launch_bounds__(256) void k_cast_x(const float4* __restrict__ x,
                                                half4v* __restrict__ xh, int n4) {
  int i = blockIdx.x * 256 + threadIdx.x;
  if (i < n4) {
    float4 v = x[i];
    half4v o;
    o[0] = (_Float16)v.x; o[1] = (_Float16)v.y; o[2] = (_Float16)v.z; o[3] = (_Float16)v.w;
    xh[i] = o;
  }
}

// Concat input-projection weights [1536][512] fp16; bias = bih + (bhh for r,z only)
__global__ __launch_bounds__(256) void k_prep_wih(const float* __restrict__ wf,
                                                  const float* __restrict__ wr,
                                                  const float* __restrict__ bf_,
                                                  const float* __restrict__ br_,
                                                  const float* __restrict__ bhf,
                                                  const float* __restrict__ bhr,
                                                  _Float16* __restrict__ wcat,
                                                  float* __restrict__ bcat) {
  int idx = blockIdx.x * 256 + threadIdx.x;     // < 1536*512
  int n = idx >> 9;
  float v = (n < 768) ? wf[idx] : wr[idx - 768 * 512];
  wcat[idx] = (_Float16)v;
  if (idx < 1536) {
    float b;
    if (idx < 768) b = bf_[idx] + ((idx < 512) ? bhf[idx] : 0.f);
    else { int i2 = idx - 768; b = br_[i2] + ((i2 < 512) ? bhr[i2] : 0.f); }
    bcat[idx] = b;
  }
}

// Pack w_hh into MFMA B-fragment order: [dir][T(16)][gate(3)][kf(8)][lane(64)][i(8)]
__global__ __launch_bounds__(256) void k_prep_whh(const float* __restrict__ whf,
                                                  const float* __restrict__ whr,
                                                  _Float16* __restrict__ whp) {
  int e = blockIdx.x * 256 + threadIdx.x;       // < 2*196608
  int dir = e / 196608;
  int r = e - dir * 196608;
  int w = r / 12288;  int r2 = r - w * 12288;
  int gate = r2 >> 12; int r3 = r2 & 4095;
  int kf = r3 >> 9;    int r4 = r3 & 511;
  int lane = r4 >> 3;  int i = r4 & 7;
  int row = gate * 256 + w * 16 + (lane & 15);
  int col = kf * 32 + (lane >> 4) * 8 + i;
  const float* src = dir ? whr : whf;
  whp[e] = (_Float16)src[row * 256 + col];
}

// ---------------------------- xi GEMM (m97 structure) ----------------------
// XCD-aware remap (R7): the 12 N-blocks sharing an A-tile run consecutively
// on one XCD -> A-tile L2-resident across its 12 consumers.
__global__ __launch_bounds__(256) void k_gemm(const _Float16* __restrict__ A,
                                              const _Float16* __restrict__ Wt,
                                              const float* __restrict__ bias,
                                              _Float16* __restrict__ C) {
  __shared__ __align__(16) _Float16 As[128 * 32];
  __shared__ __align__(16) _Float16 Bs[128 * 32];
  const int tid = threadIdx.x;
  const int wv = tid >> 6, ln = tid & 63;
  const int wm = wv >> 1, wn = wv & 1;
  const int jl = ln & 15, q = ln >> 4;

  const int lid  = blockIdx.x + 400 * blockIdx.y;   // dispatch order
  const int xcd  = lid & 7;
  const int slot = lid >> 3;                        // 0..599
  const int mi   = xcd * 50 + (slot / 12);          // 0..399
  const int ni   = slot % 12;                       // 0..11
  const int m0 = mi * 128, n0 = ni * 128;

  const int r0 = tid >> 2, k80 = (tid & 3) * 8;
  const int r1 = r0 + 64;

  fx4 acc[4][4];
#pragma unroll
  for (int a = 0; a < 4; ++a)
#pragma unroll
    for (int b = 0; b < 4; ++b) acc[a][b] = (fx4){0.f, 0.f, 0.f, 0.f};

  for (int kk = 0; kk < KDIM; kk += 32) {
    gload_lds16(A  + (size_t)(m0 + r0) * KDIM + kk + k80, As + tid * 8);
    gload_lds16(A  + (size_t)(m0 + r1) * KDIM + kk + k80, As + (tid + 256) * 8);
    gload_lds16(Wt + (size_t)(n0 + r0) * KDIM + kk + k80, Bs + tid * 8);
    gload_lds16(Wt + (size_t)(n0 + r1) * KDIM + kk + k80, Bs + (tid + 256) * 8);
    __syncthreads();
    half8 af[4], bfr[4];
#pragma unroll
    for (int mt = 0; mt < 4; ++mt)
      af[mt] = *(const half8*)(As + (wm * 64 + mt * 16 + jl) * 32 + q * 8);
#pragma unroll
    for (int nt = 0; nt < 4; ++nt)
      bfr[nt] = *(const half8*)(Bs + (wn * 64 + nt * 16 + jl) * 32 + q * 8);
#pragma unroll
    for (int mt = 0; mt < 4; ++mt)
#pragma unroll
      for (int nt = 0; nt < 4; ++nt)
        acc[mt][nt] = __builtin_amdgcn_mfma_f32_16x16x32_f16(af[mt], bfr[nt], acc[mt][nt], 0, 0, 0);
    __syncthreads();
  }

  float bsv[4];
#pragma unroll
  for (int nt = 0; nt < 4; ++nt) bsv[nt] = bias[n0 + wn * 64 + nt * 16 + jl];

  for (int mt = 0; mt < 4; ++mt) {
#pragma unroll
    for (int nt = 0; nt < 4; ++nt)
#pragma unroll
      for (int rg = 0; rg < 4; ++rg)
        As[(wm * 16 + q * 4 + rg) * 128 + wn * 64 + nt * 16 + jl] =
            (_Float16)(acc[mt][nt][rg] + bsv[nt]);
    __syncthreads();
#pragma unroll
    for (int i = 0; i < 2; ++i) {
      int idx = i * 256 + tid;
      int rl = idx >> 4, c8 = idx & 15;
      int grow = m0 + (rl >> 4) * 64 + mt * 16 + (rl & 15);
      *(half8*)(C + (size_t)grow * NG + n0 + c8 * 8) = *(const half8*)(As + rl * 128 + c8 * 8);
    }
    __syncthreads();
  }
}

// ---------------------------- GRU recurrence -------------------------------
// 32 blocks (16 batch-tiles x 2 dirs) x 512 threads (8 waves, 2/SIMD).
// Wave w owns hidden [32w, 32w+32) = 2 tiles. ALL 3 gate weight sets pinned
// in registers (48 half8 = 192 regs); no weight LDS at all. h: 16KB LDS
// double-buffer, XOR chunk swizzle; hprev in regs; xi folded into acc init;
// custom lgkm-only barrier.
// NOTE (R7 post-mortem): do NOT unroll the t-loop or remove the cx<-nx
// copies - the copy at step end is the vmcnt fence placement that hides the
// xi-prefetch HBM latency under the epilogue. Removing it cost 30%.
__global__ __launch_bounds__(512) __attribute__((amdgpu_waves_per_eu(2, 2)))
void k_gru(const _Float16* __restrict__ xi,
           const _Float16* __restrict__ whp,
           const float* __restrict__ bhhf,
           const float* __restrict__ bhhr,
           _Float16* __restrict__ out) {
  __shared__ __align__(16) _Float16 hs[8192];   // 2 x 4096 halves = 16 KB
  _Float16* hb0 = hs;
  _Float16* hb1 = hs + 4096;

  const int tid = threadIdx.x, w = tid >> 6, ln = tid & 63;
  const int jl = ln & 15, q = ln >> 4;
  const int bt = blockIdx.x, dir = blockIdx.y;
  const float* bhh = dir ? bhhr : bhhf;

  // ---- weights: all 3 gates pinned in registers [tile][gate][kf] ----
  half8 wgt[2][3][8];   // 48 half8 = 192 regs
#pragma unroll
  for (int tt = 0; tt < 2; ++tt) {
    const _Float16* wb = whp + ((size_t)(dir * 16 + w * 2 + tt)) * 12288;
#pragma unroll
    for (int g = 0; g < 3; ++g)
#pragma unroll
      for (int kf = 0; kf < 8; ++kf) {
        wgt[tt][g][kf] = *(const half8*)(wb + g * 4096 + kf * 512 + ln * 8);
        asm volatile("" : "+v"(wgt[tt][g][kf]));   // pin: opaque def, no remat
      }
  }
  float bhn[2];
#pragma unroll
  for (int tt = 0; tt < 2; ++tt) bhn[tt] = bhh[512 + w * 32 + tt * 16 + jl];

  for (int i = tid; i < 4096; i += 512) hb0[i] = (_Float16)0.f;

  // ---- xi pointers (per batch-row rg) + preload t0 ----
  const long long t0 = dir ? (SEQ - 1) : 0;
  const int xstep = dir ? -NG : NG;
  const int wcol = w * 32 + jl;
  const _Float16* xp[4];
#pragma unroll
  for (int rg = 0; rg < 4; ++rg)
    xp[rg] = xi + ((size_t)((bt * 16 + q * 4 + rg) * SEQ) + t0) * NG + dir * 768;

  _Float16 cx[2][3][4];   // current step xi [tile][gate][rg]
#pragma unroll
  for (int rg = 0; rg < 4; ++rg)
#pragma unroll
    for (int tt = 0; tt < 2; ++tt)
#pragma unroll
      for (int g = 0; g < 3; ++g)
        cx[tt][g][rg] = xp[rg][g * 256 + wcol + tt * 16];

  // ---- coalesced out-store mapping (1 step delayed) ----
  const int orow = tid >> 5, oc = tid & 31;
  _Float16* op = out + ((size_t)((bt * 16 + orow) * SEQ) + t0) * 512 + dir * 256 + oc * 8;
  const int ostep = dir ? -512 : 512;
  const int oaddr = orow * 256 + ((oc ^ (orow & 7)) << 3);   // swizzled LDS src

  float hprev[2][4] = {{0.f,0.f,0.f,0.f},{0.f,0.f,0.f,0.f}};
  __syncthreads();   // hb0 ready

  for (int t = 0; t < SEQ; ++t) {
    const _Float16* hr = (t & 1) ? hb1 : hb0;
    _Float16*       hw = (t & 1) ? hb0 : hb1;

    // prefetch xi(t+1) into regs; stays in flight across gru_barrier
    _Float16 nx[2][3][4];
    if (t < SEQ - 1) {
#pragma unroll
      for (int rg = 0; rg < 4; ++rg) {
        const _Float16* p = xp[rg] + xstep;
#pragma unroll
        for (int tt = 0; tt < 2; ++tt)
#pragma unroll
          for (int g = 0; g < 3; ++g)
            nx[tt][g][rg] = p[g * 256 + wcol + tt * 16];
      }
    }

    // acc init: r/z = xi (has all biases), n = bhh_n (xi_n added in epilogue)
    fx4 acc[2][3];
#pragma unroll
    for (int tt = 0; tt < 2; ++tt)
#pragma unroll
      for (int rg = 0; rg < 4; ++rg) {
        acc[tt][0][rg] = (float)cx[tt][0][rg];
        acc[tt][1][rg] = (float)cx[tt][1][rg];
        acc[tt][2][rg] = bhn[tt];
      }

    // store h(t-1) to global (hr holds h(t-1))
    if (t > 0) {
      *(half8*)op = *(const half8*)(hr + oaddr);
      op += ostep;
    }

#pragma unroll
    for (int kf = 0; kf < 8; ++kf) {
      int cc = kf * 4 + q;                 // k-chunk 0..31
      half8 a = *(const half8*)(hr + jl * 256 + ((cc ^ (jl & 7)) << 3));
      acc[0][0] = __builtin_amdgcn_mfma_f32_16x16x32_f16(a, wgt[0][0][kf], acc[0][0], 0, 0, 0);
      acc[0][1] = __builtin_amdgcn_mfma_f32_16x16x32_f16(a, wgt[0][1][kf], acc[0][1], 0, 0, 0);
      acc[0][2] = __builtin_amdgcn_mfma_f32_16x16x32_f16(a, wgt[0][2][kf], acc[0][2], 0, 0, 0);
      acc[1][0] = __builtin_amdgcn_mfma_f32_16x16x32_f16(a, wgt[1][0][kf], acc[1][0], 0, 0, 0);
      acc[1][1] = __builtin_amdgcn_mfma_f32_16x16x32_f16(a, wgt[1][1][kf], acc[1][1], 0, 0, 0);
      acc[1][2] = __builtin_amdgcn_mfma_f32_16x16x32_f16(a, wgt[1][2][kf], acc[1][2], 0, 0, 0);
    }

#pragma unroll
    for (int tt = 0; tt < 2; ++tt) {
      const int col = wcol + tt * 16;
      const int chunk = col >> 3;
#pragma unroll
      for (int rg = 0; rg < 4; ++rg) {
        const int rr = q * 4 + rg;
        const int haddr = rr * 256 + ((chunk ^ (rr & 7)) << 3) + (jl & 7);
        float rv = __builtin_amdgcn_rcpf(1.f + __expf(-acc[tt][0][rg]));
        float zv = __builtin_amdgcn_rcpf(1.f + __expf(-acc[tt][1][rg]));
        float gn = fmaf(rv, acc[tt][2][rg], (float)cx[tt][2][rg]);
        float e2 = __expf(2.f * gn);
        float nn = fmaf(-2.f, __builtin_amdgcn_rcpf(e2 + 1.f), 1.f);  // tanh
        float hp = hprev[tt][rg];
        float h = fmaf(zv, hp - nn, nn);
        hprev[tt][rg] = h;
        hw[haddr] = (_Float16)h;
      }
    }
#pragma unroll
    for (int rg = 0; rg < 4; ++rg) {
      xp[rg] += (t < SEQ - 1) ? xstep : 0;
#pragma unroll
      for (int tt = 0; tt < 2; ++tt)
#pragma unroll
        for (int g = 0; g < 3; ++g) cx[tt][g][rg] = nx[tt][g][rg];
    }
    gru_barrier();   // lgkm-only: h(t) visible, xi prefetch stays in flight
  }
  // flush h(SEQ-1): written at t=199 into hb0
  *(half8*)op = *(const half8*)(hb0 + oaddr);
}

// ---------------------------- heads ----------------------------------------

// 3200 blocks x 256 thr; each wave handles 4 (b,t) rows, fc weights cached in
// per-thread registers (cols ln*8..ln*8+7) -> 4x less L2 broadcast traffic.
__global__ __launch_bounds__(256) void k_heads1(const _Float16* __restrict__ out,
                                                const float* __restrict__ fc1w,
                                                const float* __restrict__ fc1b,
                                                const float* __restrict__ fc2w,
                                                const float* __restrict__ fc2b,
                                                float* __restrict__ y,
                                                float* __restrict__ y2) {
  const int tid = threadIdx.x, wv = tid >> 6, ln = tid & 63;

  float4 w1a = *(const float4*)(fc1w + ln * 8);
  float4 w1b = *(const float4*)(fc1w + ln * 8 + 4);
  float4 wa[10], wb[10];
#pragma unroll
  for (int c = 0; c < 10; ++c) {
    wa[c] = *(const float4*)(fc2w + c * 512 + ln * 8);
    wb[c] = *(const float4*)(fc2w + c * 512 + ln * 8 + 4);
  }
  float b1 = fc1b[0];
  float b2[10];
#pragma unroll
  for (int c = 0; c < 10; ++c) b2[c] = fc2b[c];

#pragma unroll
  for (int i = 0; i < 4; ++i) {
    int gw = blockIdx.x * 16 + wv * 4 + i;
    int b = gw / SEQ, t = gw - b * SEQ;
    half8 ov = *(const half8*)(out + (size_t)gw * 512 + ln * 8);
    float o[8];
#pragma unroll
    for (int k = 0; k < 8; ++k) o[k] = (float)ov[k];

    float s1 = o[0]*w1a.x + o[1]*w1a.y + o[2]*w1a.z + o[3]*w1a.w
             + o[4]*w1b.x + o[5]*w1b.y + o[6]*w1b.z + o[7]*w1b.w;
    float s2[10];
#pragma unroll
    for (int c = 0; c < 10; ++c) {
      s2[c] = o[0]*wa[c].x + o[1]*wa[c].y + o[2]*wa[c].z + o[3]*wa[c].w
            + o[4]*wb[c].x + o[5]*wb[c].y + o[6]*wb[c].z + o[7]*wb[c].w;
    }
#pragma unroll
    for (int m = 32; m; m >>= 1) {
      s1 += __shfl_xor(s1, m);
#pragma unroll
      for (int c = 0; c < 10; ++c) s2[c] += __shfl_xor(s2[c], m);
    }
    if (ln == 0) {
      y[gw] = s1 + b1;
      float* y2p = y2 + (size_t)b * 2000 + t * 10;
#pragma unroll
      for (int c = 0; c < 10; ++c) y2p[c] = s2[c] + b2[c];
    }
  }
}

__device__ __forceinline__ float blkRedMax(float v, float* red, int tid) {
#pragma unroll
  for (int m = 32; m; m >>= 1) v = fmaxf(v, __shfl_xor(v, m));
  __syncthreads();
  if ((tid & 63) == 0) red[tid >> 6] = v;
  __syncthreads();
  return fmaxf(fmaxf(red[0], red[1]), fmaxf(red[2], red[3]));
}
__device__ __forceinline__ float blkRedSum(float v, float* red, int tid) {
#pragma unroll
  for (int m = 32; m; m >>= 1) v += __shfl_xor(v, m);
  __syncthreads();
  if ((tid & 63) == 0) red[tid >> 6] = v;
  __syncthreads();
  return red[0] + red[1] + red[2] + red[3];
}

__global__ __launch_bounds__(256) void k_heads2(const float* __restrict__ y,
                                                const float* __restrict__ y2,
                                                float* __restrict__ y3) {
  __shared__ float sp[SEQ];
  __shared__ float se[2000];
  __shared__ float red[4];
  int b = blockIdx.x, tid = threadIdx.x;

  float v = (tid < SEQ) ? y[(size_t)b * SEQ + tid] : -3.0e38f;
  float mx = blkRedMax(v, red, tid);
  float e = (tid < SEQ) ? __expf(v - mx) : 0.f;
  float sum = blkRedSum(e, red, tid);
  if (tid < SEQ) sp[tid] = e / (sum * 10.f);

  float vv[8];
  float lm = -3.0e38f;
#pragma unroll
  for (int r = 0; r < 8; ++r) {
    int k = tid + r * 256;
    vv[r] = (k < 2000) ? y2[(size_t)b * 2000 + k] : -3.0e38f;
    lm = fmaxf(lm, vv[r]);
  }
  float mx2 = blkRedMax(lm, red, tid);
  float ls = 0.f;
#pragma unroll
  for (int r = 0; r < 8; ++r) {
    int k = tid + r * 256;
    if (k < 2000) { float ee = __expf(vv[r] - mx2); se[k] = ee; ls += ee; }
  }
  float sum2 = blkRedSum(ls, red, tid);
  __syncthreads();
  float inv = 1.f / sum2;
#pragma unroll
  for (int r = 0; r < 8; ++r) {
    int k = tid + r * 256;
    if (k < 2000) y3[(size_t)b * 2000 + k] = se[k] * inv + sp[k / 10];
  }
}

// ---------------------------- launch ---------------------------------------

extern "C" void kernel_launch(void* const* d_in, const int* in_sizes, int n_in,
                              void* d_out, int out_size, void* d_ws, size_t ws_size,
                              hipStream_t stream) {
  const float* x     = (const float*)d_in[0];
  const float* wih0  = (const float*)d_in[1];
  const float* whh0  = (const float*)d_in[2];
  const float* bih0  = (const float*)d_in[3];
  const float* bhh0  = (const float*)d_in[4];
  const float* wih0r = (const float*)d_in[5];
  const float* whh0r = (const float*)d_in[6];
  const float* bih0r = (const float*)d_in[7];
  const float* bhh0r = (const float*)d_in[8];
  const float* wih1  = (const float*)d_in[9];
  const float* whh1  = (const float*)d_in[10];
  const float* bih1  = (const float*)d_in[11];
  const float* bhh1  = (const float*)d_in[12];
  const float* wih1r = (const float*)d_in[13];
  const float* whh1r = (const float*)d_in[14];
  const float* bih1r = (const float*)d_in[15];
  const float* bhh1r = (const float*)d_in[16];
  const float* fc1w  = (const float*)d_in[17];
  const float* fc1b  = (const float*)d_in[18];
  const float* fc2w  = (const float*)d_in[19];
  const float* fc2b  = (const float*)d_in[20];

  char* ws = (char*)d_ws;
  _Float16* xh    = (_Float16*)(ws + 0);
  _Float16* xi    = (_Float16*)(ws + 52428800);
  _Float16* l0    = (_Float16*)(ws + 209715200);
  _Float16* outh  = (_Float16*)(ws + 262144000);
  _Float16* wcat0 = (_Float16*)(ws + 314572800);
  _Float16* wcat1 = (_Float16*)(ws + 316145664);
  _Float16* whp0  = (_Float16*)(ws + 317718528);
  _Float16* whp1  = (_Float16*)(ws + 318504960);
  float*    bcat0 = (float*)(ws + 319291392);
  float*    bcat1 = (float*)(ws + 319297536);

  float* y  = (float*)d_out;
  float* y2 = (float*)d_out + 51200;
  float* y3 = (float*)d_out + 563200;

  k_cast_x<<<25600, 256, 0, stream>>>((const float4*)x, (half4v*)xh, 6553600);
  k_prep_wih<<<3072, 256, 0, stream>>>(wih0, wih0r, bih0, bih0r, bhh0, bhh0r, wcat0, bcat0);
  k_prep_wih<<<3072, 256, 0, stream>>>(wih1, wih1r, bih1, bih1r, bhh1, bhh1r, wcat1, bcat1);
  k_prep_whh<<<1536, 256, 0, stream>>>(whh0, whh0r, whp0);
  k_prep_whh<<<1536, 256, 0, stream>>>(whh1, whh1r, whp1);

  k_gemm<<<dim3(400, 12), 256, 0, stream>>>(xh, wcat0, bcat0, xi);
  k_gru<<<dim3(16, 2), 512, 0, stream>>>(xi, whp0, bhh0, bhh0r, l0);
  k_gemm<<<dim3(400, 12), 256, 0, stream>>>(l0, wcat1, bcat1, xi);
  k_gru<<<dim3(16, 2), 512, 0, stream>>>(xi, whp1, bhh1, bhh1r, outh);
  k_heads1<<<3200, 256, 0, stream>>>(outh, fc1w, fc1b, fc2w, fc2b, y, y2);
  k_heads2<<<256, 256, 0, stream>>>(y, y2, y3);
}

// Round 8
// 1159.031 us; speedup vs baseline: 4.6335x; 2.1259x over previous
//
#include <hip/hip_runtime.h>

// ---------------------------------------------------------------------------
// Bidirectional 2-layer GRU (B=256, L=200, IN=512, H=256) + FC heads.
// R14 = R12 resubmitted a 2nd time (R12+R13 benches were infra failures:
// "container failed twice" at acquisition - kernel never compiled/ran).
// If this fails the same way, next round submits the R8 baseline to
// disambiguate infra-flake vs source-correlated failure.
// R12: R8-verified gru structure + paired xi layout.
//   xi columns permuted within each 32-col group: [tt][jl] -> [jl][tt], so
//   each gru thread's (tt0,tt1) pair is one aligned dword. 24 scalar ushort
//   loads/thread/step -> 12 dword loads (halves VMEM issue count, -12 regs).
//   Permutation applied in k_gemm's epilogue LDS-staging index only (C-write
//   stays half8-coalesced). cx<-nx copy fence preserved as 12 u32 copies.
//   R11 post-mortem: +64 weight pins exceeded the ~256/wave unified-file cap
//   at 2 waves/SIMD -> scratch spill, 2.5x slower. No more pinning headroom.
//   R9/R10: cross-block per-step sync via agent atomics ~25k cyc/step. Dead.
// ---------------------------------------------------------------------------

typedef _Float16 half8 __attribute__((ext_vector_type(8)));
typedef _Float16 half4v __attribute__((ext_vector_type(4)));
typedef float fx4 __attribute__((ext_vector_type(4)));

#define BATCH 256
#define SEQ   200
#define HID   256
#define MROWS (BATCH*SEQ)   // 51200
#define NG    1536          // 3H * 2 directions
#define KDIM  512

__device__ __forceinline__ void gload_lds16(const _Float16* g, _Float16* l) {
  __builtin_amdgcn_global_load_lds((const __attribute__((address_space(1))) void*)g,
                                   (__attribute__((address_space(3))) void*)l, 16, 0, 0);
}

// Barrier that drains only LDS ops (lgkmcnt), NOT vmcnt: global prefetch
// loads stay outstanding across the step boundary.
__device__ __forceinline__ void gru_barrier() {
  asm volatile("s_waitcnt lgkmcnt(0)\n\ts_barrier" ::: "memory");
}

__device__ __forceinline__ float lo16f(unsigned v) {
  return (float)__builtin_bit_cast(_Float16, (unsigned short)(v & 0xffffu));
}
__device__ __forceinline__ float hi16f(unsigned v) {
  return (float)__builtin_bit_cast(_Float16, (unsigned short)(v >> 16));
}

// ---------------------------- prep kernels ---------------------------------

__global__ __launch_bounds__(256) void k_cast_x(const float4* __restrict__ x,
                                                half4v* __restrict__ xh, int n4) {
  int i = blockIdx.x * 256 + threadIdx.x;
  if (i < n4) {
    float4 v = x[i];
    half4v o;
    o[0] = (_Float16)v.x; o[1] = (_Float16)v.y; o[2] = (_Float16)v.z; o[3] = (_Float16)v.w;
    xh[i] = o;
  }
}

// Concat input-projection weights [1536][512] fp16; bias = bih + (bhh for r,z only)
__global__ __launch_bounds__(256) void k_prep_wih(const float* __restrict__ wf,
                                                  const float* __restrict__ wr,
                                                  const float* __restrict__ bf_,
                                                  const float* __restrict__ br_,
                                                  const float* __restrict__ bhf,
                                                  const float* __restrict__ bhr,
                                                  _Float16* __restrict__ wcat,
                                                  float* __restrict__ bcat) {
  int idx = blockIdx.x * 256 + threadIdx.x;     // < 1536*512
  int n = idx >> 9;
  float v = (n < 768) ? wf[idx] : wr[idx - 768 * 512];
  wcat[idx] = (_Float16)v;
  if (idx < 1536) {
    float b;
    if (idx < 768) b = bf_[idx] + ((idx < 512) ? bhf[idx] : 0.f);
    else { int i2 = idx - 768; b = br_[i2] + ((i2 < 512) ? bhr[i2] : 0.f); }
    bcat[idx] = b;
  }
}

// Pack w_hh into MFMA B-fragment order: [dir][T(16)][gate(3)][kf(8)][lane(64)][i(8)]
__global__ __launch_bounds__(256) void k_prep_whh(const float* __restrict__ whf,
                                                  const float* __restrict__ whr,
                                                  _Float16* __restrict__ whp) {
  int e = blockIdx.x * 256 + threadIdx.x;       // < 2*196608
  int dir = e / 196608;
  int r = e - dir * 196608;
  int w = r / 12288;  int r2 = r - w * 12288;
  int gate = r2 >> 12; int r3 = r2 & 4095;
  int kf = r3 >> 9;    int r4 = r3 & 511;
  int lane = r4 >> 3;  int i = r4 & 7;
  int row = gate * 256 + w * 16 + (lane & 15);
  int col = kf * 32 + (lane >> 4) * 8 + i;
  const float* src = dir ? whr : whf;
  whp[e] = (_Float16)src[row * 256 + col];
}

// ---------------------------- xi GEMM (m97 structure) ----------------------
// XCD-aware remap (R7): the 12 N-blocks sharing an A-tile run consecutively
// on one XCD -> A-tile L2-resident across its 12 consumers.
// R12: epilogue stages C in the PAIRED layout: within each 32-col group,
// col = g32*32 + tt*16 + jl  ->  g32*32 + jl*2 + tt. C-write stays half8.
__global__ __launch_bounds__(256) void k_gemm(const _Float16* __restrict__ A,
                                              const _Float16* __restrict__ Wt,
                                              const float* __restrict__ bias,
                                              _Float16* __restrict__ C) {
  __shared__ __align__(16) _Float16 As[128 * 32];
  __shared__ __align__(16) _Float16 Bs[128 * 32];
  const int tid = threadIdx.x;
  const int wv = tid >> 6, ln = tid & 63;
  const int wm = wv >> 1, wn = wv & 1;
  const int jl = ln & 15, q = ln >> 4;

  const int lid  = blockIdx.x + 400 * blockIdx.y;   // dispatch order
  const int xcd  = lid & 7;
  const int slot = lid >> 3;                        // 0..599
  const int mi   = xcd * 50 + (slot / 12);          // 0..399
  const int ni   = slot % 12;                       // 0..11
  const int m0 = mi * 128, n0 = ni * 128;

  const int r0 = tid >> 2, k80 = (tid & 3) * 8;
  const int r1 = r0 + 64;

  fx4 acc[4][4];
#pragma unroll
  for (int a = 0; a < 4; ++a)
#pragma unroll
    for (int b = 0; b < 4; ++b) acc[a][b] = (fx4){0.f, 0.f, 0.f, 0.f};

  for (int kk = 0; kk < KDIM; kk += 32) {
    gload_lds16(A  + (size_t)(m0 + r0) * KDIM + kk + k80, As + tid * 8);
    gload_lds16(A  + (size_t)(m0 + r1) * KDIM + kk + k80, As + (tid + 256) * 8);
    gload_lds16(Wt + (size_t)(n0 + r0) * KDIM + kk + k80, Bs + tid * 8);
    gload_lds16(Wt + (size_t)(n0 + r1) * KDIM + kk + k80, Bs + (tid + 256) * 8);
    __syncthreads();
    half8 af[4], bfr[4];
#pragma unroll
    for (int mt = 0; mt < 4; ++mt)
      af[mt] = *(const half8*)(As + (wm * 64 + mt * 16 + jl) * 32 + q * 8);
#pragma unroll
    for (int nt = 0; nt < 4; ++nt)
      bfr[nt] = *(const half8*)(Bs + (wn * 64 + nt * 16 + jl) * 32 + q * 8);
#pragma unroll
    for (int mt = 0; mt < 4; ++mt)
#pragma unroll
      for (int nt = 0; nt < 4; ++nt)
        acc[mt][nt] = __builtin_amdgcn_mfma_f32_16x16x32_f16(af[mt], bfr[nt], acc[mt][nt], 0, 0, 0);
    __syncthreads();
  }

  float bsv[4];
#pragma unroll
  for (int nt = 0; nt < 4; ++nt) bsv[nt] = bias[n0 + wn * 64 + nt * 16 + jl];

  for (int mt = 0; mt < 4; ++mt) {
#pragma unroll
    for (int nt = 0; nt < 4; ++nt) {
      // paired-layout local col: group (wn*64 + (nt>>1)*32), then jl*2 + (nt&1)
      const int pcol = wn * 64 + (nt >> 1) * 32 + jl * 2 + (nt & 1);
#pragma unroll
      for (int rg = 0; rg < 4; ++rg)
        As[(wm * 16 + q * 4 + rg) * 128 + pcol] =
            (_Float16)(acc[mt][nt][rg] + bsv[nt]);
    }
    __syncthreads();
#pragma unroll
    for (int i = 0; i < 2; ++i) {
      int idx = i * 256 + tid;
      int rl = idx >> 4, c8 = idx & 15;
      int grow = m0 + (rl >> 4) * 64 + mt * 16 + (rl & 15);
      *(half8*)(C + (size_t)grow * NG + n0 + c8 * 8) = *(const half8*)(As + rl * 128 + c8 * 8);
    }
    __syncthreads();
  }
}

// ---------------------------- GRU recurrence -------------------------------
// 32 blocks (16 batch-tiles x 2 dirs) x 512 threads (8 waves, 2/SIMD).
// Wave w owns hidden [32w, 32w+32) = 2 tiles. r,z weights pinned in VGPRs;
// n weights in LDS. h: LDS double-buffer, XOR chunk swizzle; hprev in regs;
// xi folded into acc init; custom lgkm-only barrier.
// R12: xi in paired layout -> 12 dword loads/thread/step (was 24 ushort).
// NOTE (R7 post-mortem): do NOT unroll the t-loop or remove the cx<-nx
// copies - the copy at step end is the vmcnt fence placement that hides the
// xi-prefetch HBM latency under the epilogue. Removing it cost 30%.
__global__ __launch_bounds__(512) __attribute__((amdgpu_waves_per_eu(2, 2)))
void k_gru(const _Float16* __restrict__ xi,
           const _Float16* __restrict__ whp,
           const float* __restrict__ bhhf,
           const float* __restrict__ bhhr,
           _Float16* __restrict__ out) {
  extern __shared__ _Float16 smem[];
  _Float16* nlds = smem;                  // 16*8*512 = 65536 halves (128 KB)
  _Float16* hb0  = smem + 65536;          // 16 rows * 256 = 4096
  _Float16* hb1  = smem + 69632;          // 4096  -> total 147456 B

  const int tid = threadIdx.x, w = tid >> 6, ln = tid & 63;
  const int jl = ln & 15, q = ln >> 4;
  const int bt = blockIdx.x, dir = blockIdx.y;
  const float* bhh = dir ? bhhr : bhhf;

  // ---- weights: r,z pinned VGPR; n -> LDS ----
  half8 wrz[2][2][8];   // [tile][gate r/z][kf] = 32 half8 = 128 VGPRs
#pragma unroll
  for (int tt = 0; tt < 2; ++tt) {
    const _Float16* wb = whp + ((size_t)(dir * 16 + w * 2 + tt)) * 12288;
#pragma unroll
    for (int g = 0; g < 2; ++g)
#pragma unroll
      for (int kf = 0; kf < 8; ++kf) {
        wrz[tt][g][kf] = *(const half8*)(wb + g * 4096 + kf * 512 + ln * 8);
        asm volatile("" : "+v"(wrz[tt][g][kf]));   // pin: opaque def, no remat
      }
#pragma unroll
    for (int kf = 0; kf < 8; ++kf)
      *(half8*)(nlds + ((w * 2 + tt) * 8 + kf) * 512 + ln * 8) =
          *(const half8*)(wb + 2 * 4096 + kf * 512 + ln * 8);
  }
  float bhn[2];
#pragma unroll
  for (int tt = 0; tt < 2; ++tt) bhn[tt] = bhh[512 + w * 32 + tt * 16 + jl];

  for (int i = tid; i < 4096; i += 512) hb0[i] = (_Float16)0.f;

  // ---- xi pointers (per batch-row rg) + preload t0 (paired layout) ----
  const long long t0 = dir ? (SEQ - 1) : 0;
  const int xstep = dir ? -NG : NG;
  const int wcol2 = w * 32 + jl * 2;      // paired: tt in low/high half of dword
  const _Float16* xp[4];
#pragma unroll
  for (int rg = 0; rg < 4; ++rg)
    xp[rg] = xi + ((size_t)((bt * 16 + q * 4 + rg) * SEQ) + t0) * NG + dir * 768;

  unsigned cx[3][4];   // current step xi [gate][rg]; lo16 = tt0, hi16 = tt1
#pragma unroll
  for (int rg = 0; rg < 4; ++rg)
#pragma unroll
    for (int g = 0; g < 3; ++g)
      cx[g][rg] = *(const unsigned*)(xp[rg] + g * 256 + wcol2);

  // ---- coalesced out-store mapping (1 step delayed) ----
  const int orow = tid >> 5, oc = tid & 31;
  _Float16* op = out + ((size_t)((bt * 16 + orow) * SEQ) + t0) * 512 + dir * 256 + oc * 8;
  const int ostep = dir ? -512 : 512;
  const int oaddr = orow * 256 + ((oc ^ (orow & 7)) << 3);   // swizzled LDS src

  float hprev[2][4] = {{0.f,0.f,0.f,0.f},{0.f,0.f,0.f,0.f}};
  __syncthreads();   // nlds + hb0 ready (full barrier once)

  for (int t = 0; t < SEQ; ++t) {
    const _Float16* hr = (t & 1) ? hb1 : hb0;
    _Float16*       hw = (t & 1) ? hb0 : hb1;

    // prefetch xi(t+1) into regs; stays in flight across gru_barrier
    unsigned nx[3][4];
    if (t < SEQ - 1) {
#pragma unroll
      for (int rg = 0; rg < 4; ++rg) {
        const _Float16* p = xp[rg] + xstep;
#pragma unroll
        for (int g = 0; g < 3; ++g)
          nx[g][rg] = *(const unsigned*)(p + g * 256 + wcol2);
      }
    }

    // acc init: r/z = xi (has all biases), n = bhh_n (xi_n added in epilogue)
    fx4 acc[2][3];
#pragma unroll
    for (int rg = 0; rg < 4; ++rg) {
      const unsigned c0 = cx[0][rg], c1 = cx[1][rg];
      acc[0][0][rg] = lo16f(c0);
      acc[1][0][rg] = hi16f(c0);
      acc[0][1][rg] = lo16f(c1);
      acc[1][1][rg] = hi16f(c1);
      acc[0][2][rg] = bhn[0];
      acc[1][2][rg] = bhn[1];
    }

    // store h(t-1) to global (hr holds h(t-1))
    if (t > 0) {
      *(half8*)op = *(const half8*)(hr + oaddr);
      op += ostep;
    }

#pragma unroll
    for (int kf = 0; kf < 8; ++kf) {
      int cc = kf * 4 + q;                 // k-chunk 0..31
      half8 a = *(const half8*)(hr + jl * 256 + ((cc ^ (jl & 7)) << 3));
      half8 nb0 = *(const half8*)(nlds + ((w * 2 + 0) * 8 + kf) * 512 + ln * 8);
      half8 nb1 = *(const half8*)(nlds + ((w * 2 + 1) * 8 + kf) * 512 + ln * 8);
      acc[0][0] = __builtin_amdgcn_mfma_f32_16x16x32_f16(a, wrz[0][0][kf], acc[0][0], 0, 0, 0);
      acc[0][1] = __builtin_amdgcn_mfma_f32_16x16x32_f16(a, wrz[0][1][kf], acc[0][1], 0, 0, 0);
      acc[0][2] = __builtin_amdgcn_mfma_f32_16x16x32_f16(a, nb0,           acc[0][2], 0, 0, 0);
      acc[1][0] = __builtin_amdgcn_mfma_f32_16x16x32_f16(a, wrz[1][0][kf], acc[1][0], 0, 0, 0);
      acc[1][1] = __builtin_amdgcn_mfma_f32_16x16x32_f16(a, wrz[1][1][kf], acc[1][1], 0, 0, 0);
      acc[1][2] = __builtin_amdgcn_mfma_f32_16x16x32_f16(a, nb1,           acc[1][2], 0, 0, 0);
    }

#pragma unroll
    for (int tt = 0; tt < 2; ++tt) {
      const int col = w * 32 + jl + tt * 16;
      const int chunk = col >> 3;
#pragma unroll
      for (int rg = 0; rg < 4; ++rg) {
        const int rr = q * 4 + rg;
        const int haddr = rr * 256 + ((chunk ^ (rr & 7)) << 3) + (jl & 7);
        float xn = tt ? hi16f(cx[2][rg]) : lo16f(cx[2][rg]);
        float rv = __builtin_amdgcn_rcpf(1.f + __expf(-acc[tt][0][rg]));
        float zv = __builtin_amdgcn_rcpf(1.f + __expf(-acc[tt][1][rg]));
        float gn = fmaf(rv, acc[tt][2][rg], xn);
        float e2 = __expf(2.f * gn);
        float nn = fmaf(-2.f, __builtin_amdgcn_rcpf(e2 + 1.f), 1.f);  // tanh
        float hp = hprev[tt][rg];
        float h = fmaf(zv, hp - nn, nn);
        hprev[tt][rg] = h;
        hw[haddr] = (_Float16)h;
      }
    }
#pragma unroll
    for (int rg = 0; rg < 4; ++rg) {
      xp[rg] += (t < SEQ - 1) ? xstep : 0;
#pragma unroll
      for (int g = 0; g < 3; ++g) cx[g][rg] = nx[g][rg];
    }
    gru_barrier();   // lgkm-only: h(t) visible, xi prefetch stays in flight
  }
  // flush h(SEQ-1): written at t=199 into hb0
  *(half8*)op = *(const half8*)(hb0 + oaddr);
}

// ---------------------------- heads ----------------------------------------

// 3200 blocks x 256 thr; each wave handles 4 (b,t) rows, fc weights cached in
// per-thread registers (cols ln*8..ln*8+7) -> 4x less L2 broadcast traffic.
__global__ __launch_bounds__(256) void k_heads1(const _Float16* __restrict__ out,
                                                const float* __restrict__ fc1w,
                                                const float* __restrict__ fc1b,
                                                const float* __restrict__ fc2w,
                                                const float* __restrict__ fc2b,
                                                float* __restrict__ y,
                                                float* __restrict__ y2) {
  const int tid = threadIdx.x, wv = tid >> 6, ln = tid & 63;

  float4 w1a = *(const float4*)(fc1w + ln * 8);
  float4 w1b = *(const float4*)(fc1w + ln * 8 + 4);
  float4 wa[10], wb[10];
#pragma unroll
  for (int c = 0; c < 10; ++c) {
    wa[c] = *(const float4*)(fc2w + c * 512 + ln * 8);
    wb[c] = *(const float4*)(fc2w + c * 512 + ln * 8 + 4);
  }
  float b1 = fc1b[0];
  float b2[10];
#pragma unroll
  for (int c = 0; c < 10; ++c) b2[c] = fc2b[c];

#pragma unroll
  for (int i = 0; i < 4; ++i) {
    int gw = blockIdx.x * 16 + wv * 4 + i;
    int b = gw / SEQ, t = gw - b * SEQ;
    half8 ov = *(const half8*)(out + (size_t)gw * 512 + ln * 8);
    float o[8];
#pragma unroll
    for (int k = 0; k < 8; ++k) o[k] = (float)ov[k];

    float s1 = o[0]*w1a.x + o[1]*w1a.y + o[2]*w1a.z + o[3]*w1a.w
             + o[4]*w1b.x + o[5]*w1b.y + o[6]*w1b.z + o[7]*w1b.w;
    float s2[10];
#pragma unroll
    for (int c = 0; c < 10; ++c) {
      s2[c] = o[0]*wa[c].x + o[1]*wa[c].y + o[2]*wa[c].z + o[3]*wa[c].w
            + o[4]*wb[c].x + o[5]*wb[c].y + o[6]*wb[c].z + o[7]*wb[c].w;
    }
#pragma unroll
    for (int m = 32; m; m >>= 1) {
      s1 += __shfl_xor(s1, m);
#pragma unroll
      for (int c = 0; c < 10; ++c) s2[c] += __shfl_xor(s2[c], m);
    }
    if (ln == 0) {
      y[gw] = s1 + b1;
      float* y2p = y2 + (size_t)b * 2000 + t * 10;
#pragma unroll
      for (int c = 0; c < 10; ++c) y2p[c] = s2[c] + b2[c];
    }
  }
}

__device__ __forceinline__ float blkRedMax(float v, float* red, int tid) {
#pragma unroll
  for (int m = 32; m; m >>= 1) v = fmaxf(v, __shfl_xor(v, m));
  __syncthreads();
  if ((tid & 63) == 0) red[tid >> 6] = v;
  __syncthreads();
  return fmaxf(fmaxf(red[0], red[1]), fmaxf(red[2], red[3]));
}
__device__ __forceinline__ float blkRedSum(float v, float* red, int tid) {
#pragma unroll
  for (int m = 32; m; m >>= 1) v += __shfl_xor(v, m);
  __syncthreads();
  if ((tid & 63) == 0) red[tid >> 6] = v;
  __syncthreads();
  return red[0] + red[1] + red[2] + red[3];
}

__global__ __launch_bounds__(256) void k_heads2(const float* __restrict__ y,
                                                const float* __restrict__ y2,
                                                float* __restrict__ y3) {
  __shared__ float sp[SEQ];
  __shared__ float se[2000];
  __shared__ float red[4];
  int b = blockIdx.x, tid = threadIdx.x;

  float v = (tid < SEQ) ? y[(size_t)b * SEQ + tid] : -3.0e38f;
  float mx = blkRedMax(v, red, tid);
  float e = (tid < SEQ) ? __expf(v - mx) : 0.f;
  float sum = blkRedSum(e, red, tid);
  if (tid < SEQ) sp[tid] = e / (sum * 10.f);

  float vv[8];
  float lm = -3.0e38f;
#pragma unroll
  for (int r = 0; r < 8; ++r) {
    int k = tid + r * 256;
    vv[r] = (k < 2000) ? y2[(size_t)b * 2000 + k] : -3.0e38f;
    lm = fmaxf(lm, vv[r]);
  }
  float mx2 = blkRedMax(lm, red, tid);
  float ls = 0.f;
#pragma unroll
  for (int r = 0; r < 8; ++r) {
    int k = tid + r * 256;
    if (k < 2000) { float ee = __expf(vv[r] - mx2); se[k] = ee; ls += ee; }
  }
  float sum2 = blkRedSum(ls, red, tid);
  __syncthreads();
  float inv = 1.f / sum2;
#pragma unroll
  for (int r = 0; r < 8; ++r) {
    int k = tid + r * 256;
    if (k < 2000) y3[(size_t)b * 2000 + k] = se[k] * inv + sp[k / 10];
  }
}

// ---------------------------- launch ---------------------------------------

extern "C" void kernel_launch(void* const* d_in, const int* in_sizes, int n_in,
                              void* d_out, int out_size, void* d_ws, size_t ws_size,
                              hipStream_t stream) {
  const float* x     = (const float*)d_in[0];
  const float* wih0  = (const float*)d_in[1];
  const float* whh0  = (const float*)d_in[2];
  const float* bih0  = (const float*)d_in[3];
  const float* bhh0  = (const float*)d_in[4];
  const float* wih0r = (const float*)d_in[5];
  const float* whh0r = (const float*)d_in[6];
  const float* bih0r = (const float*)d_in[7];
  const float* bhh0r = (const float*)d_in[8];
  const float* wih1  = (const float*)d_in[9];
  const float* whh1  = (const float*)d_in[10];
  const float* bih1  = (const float*)d_in[11];
  const float* bhh1  = (const float*)d_in[12];
  const float* wih1r = (const float*)d_in[13];
  const float* whh1r = (const float*)d_in[14];
  const float* bih1r = (const float*)d_in[15];
  const float* bhh1r = (const float*)d_in[16];
  const float* fc1w  = (const float*)d_in[17];
  const float* fc1b  = (const float*)d_in[18];
  const float* fc2w  = (const float*)d_in[19];
  const float* fc2b  = (const float*)d_in[20];

  char* ws = (char*)d_ws;
  _Float16* xh    = (_Float16*)(ws + 0);
  _Float16* xi    = (_Float16*)(ws + 52428800);
  _Float16* l0    = (_Float16*)(ws + 209715200);
  _Float16* outh  = (_Float16*)(ws + 262144000);
  _Float16* wcat0 = (_Float16*)(ws + 314572800);
  _Float16* wcat1 = (_Float16*)(ws + 316145664);
  _Float16* whp0  = (_Float16*)(ws + 317718528);
  _Float16* whp1  = (_Float16*)(ws + 318504960);
  float*    bcat0 = (float*)(ws + 319291392);
  float*    bcat1 = (float*)(ws + 319297536);

  float* y  = (float*)d_out;
  float* y2 = (float*)d_out + 51200;
  float* y3 = (float*)d_out + 563200;

  k_cast_x<<<25600, 256, 0, stream>>>((const float4*)x, (half4v*)xh, 6553600);
  k_prep_wih<<<3072, 256, 0, stream>>>(wih0, wih0r, bih0, bih0r, bhh0, bhh0r, wcat0, bcat0);
  k_prep_wih<<<3072, 256, 0, stream>>>(wih1, wih1r, bih1, bih1r, bhh1, bhh1r, wcat1, bcat1);
  k_prep_whh<<<1536, 256, 0, stream>>>(whh0, whh0r, whp0);
  k_prep_whh<<<1536, 256, 0, stream>>>(whh1, whh1r, whp1);

  hipFuncSetAttribute(reinterpret_cast<const void*>(k_gru),
                      hipFuncAttributeMaxDynamicSharedMemorySize, 147456);

  k_gemm<<<dim3(400, 12), 256, 0, stream>>>(xh, wcat0, bcat0, xi);
  k_gru<<<dim3(16, 2), 512, 147456, stream>>>(xi, whp0, bhh0, bhh0r, l0);
  k_gemm<<<dim3(400, 12), 256, 0, stream>>>(l0, wcat1, bcat1, xi);
  k_gru<<<dim3(16, 2), 512, 147456, stream>>>(xi, whp1, bhh1, bhh1r, outh);
  k_heads1<<<3200, 256, 0, stream>>>(outh, fc1w, fc1b, fc2w, fc2b, y, y2);
  k_heads2<<<256, 256, 0, stream>>>(y, y2, y3);
}

// Round 9
// 1156.403 us; speedup vs baseline: 4.6441x; 1.0023x over previous
//
#include <hip/hip_runtime.h>

// ---------------------------------------------------------------------------
// Bidirectional 2-layer GRU (B=256, L=200, IN=512, H=256) + FC heads.
// R15: k_gru FROZEN at R14 (362us/dispatch, verified). k_gemm epilogue
//   rewritten: the R12 paired C layout puts (nt even, nt odd) in adjacent
//   global columns, so each thread packs the pair into a dword and stores
//   DIRECTLY to global (32 dword stores, 64B-coalesced per lane group).
//   Deletes the 4-pass LDS staging: 64 scalar ds_write_b16 + 16 LDS reads
//   + 8 epilogue barriers per block -> zero.
//   History: R14 paired-xi = -41us/gru (verified). R11 full-pin = spill/stall
//   (dead). R9/R10 cross-block sync = ~25k cyc/step (dead). R7 t-unroll =
//   fence-placement regression (never unroll the t-loop).
// ---------------------------------------------------------------------------

typedef _Float16 half8 __attribute__((ext_vector_type(8)));
typedef _Float16 half4v __attribute__((ext_vector_type(4)));
typedef float fx4 __attribute__((ext_vector_type(4)));

#define BATCH 256
#define SEQ   200
#define HID   256
#define MROWS (BATCH*SEQ)   // 51200
#define NG    1536          // 3H * 2 directions
#define KDIM  512

__device__ __forceinline__ void gload_lds16(const _Float16* g, _Float16* l) {
  __builtin_amdgcn_global_load_lds((const __attribute__((address_space(1))) void*)g,
                                   (__attribute__((address_space(3))) void*)l, 16, 0, 0);
}

// Barrier that drains only LDS ops (lgkmcnt), NOT vmcnt: global prefetch
// loads stay outstanding across the step boundary.
__device__ __forceinline__ void gru_barrier() {
  asm volatile("s_waitcnt lgkmcnt(0)\n\ts_barrier" ::: "memory");
}

__device__ __forceinline__ float lo16f(unsigned v) {
  return (float)__builtin_bit_cast(_Float16, (unsigned short)(v & 0xffffu));
}
__device__ __forceinline__ float hi16f(unsigned v) {
  return (float)__builtin_bit_cast(_Float16, (unsigned short)(v >> 16));
}

// ---------------------------- prep kernels ---------------------------------

__global__ __launch_bounds__(256) void k_cast_x(const float4* __restrict__ x,
                                                half4v* __restrict__ xh, int n4) {
  int i = blockIdx.x * 256 + threadIdx.x;
  if (i < n4) {
    float4 v = x[i];
    half4v o;
    o[0] = (_Float16)v.x; o[1] = (_Float16)v.y; o[2] = (_Float16)v.z; o[3] = (_Float16)v.w;
    xh[i] = o;
  }
}

// Concat input-projection weights [1536][512] fp16; bias = bih + (bhh for r,z only)
__global__ __launch_bounds__(256) void k_prep_wih(const float* __restrict__ wf,
                                                  const float* __restrict__ wr,
                                                  const float* __restrict__ bf_,
                                                  const float* __restrict__ br_,
                                                  const float* __restrict__ bhf,
                                                  const float* __restrict__ bhr,
                                                  _Float16* __restrict__ wcat,
                                                  float* __restrict__ bcat) {
  int idx = blockIdx.x * 256 + threadIdx.x;     // < 1536*512
  int n = idx >> 9;
  float v = (n < 768) ? wf[idx] : wr[idx - 768 * 512];
  wcat[idx] = (_Float16)v;
  if (idx < 1536) {
    float b;
    if (idx < 768) b = bf_[idx] + ((idx < 512) ? bhf[idx] : 0.f);
    else { int i2 = idx - 768; b = br_[i2] + ((i2 < 512) ? bhr[i2] : 0.f); }
    bcat[idx] = b;
  }
}

// Pack w_hh into MFMA B-fragment order: [dir][T(16)][gate(3)][kf(8)][lane(64)][i(8)]
__global__ __launch_bounds__(256) void k_prep_whh(const float* __restrict__ whf,
                                                  const float* __restrict__ whr,
                                                  _Float16* __restrict__ whp) {
  int e = blockIdx.x * 256 + threadIdx.x;       // < 2*196608
  int dir = e / 196608;
  int r = e - dir * 196608;
  int w = r / 12288;  int r2 = r - w * 12288;
  int gate = r2 >> 12; int r3 = r2 & 4095;
  int kf = r3 >> 9;    int r4 = r3 & 511;
  int lane = r4 >> 3;  int i = r4 & 7;
  int row = gate * 256 + w * 16 + (lane & 15);
  int col = kf * 32 + (lane >> 4) * 8 + i;
  const float* src = dir ? whr : whf;
  whp[e] = (_Float16)src[row * 256 + col];
}

// ---------------------------- xi GEMM (m97 structure) ----------------------
// XCD-aware remap (R7): the 12 N-blocks sharing an A-tile run consecutively
// on one XCD -> A-tile L2-resident across its 12 consumers.
// R12: C written in PAIRED layout: within each 32-col group,
// col = g32*32 + tt*16 + jl  ->  g32*32 + jl*2 + tt.
// R15: direct packed-dword C store from accs (no LDS staging, no epilogue
// barriers). (nt even, nt odd) = adjacent cols jl*2, jl*2+1 -> one u32.
__global__ __launch_bounds__(256) void k_gemm(const _Float16* __restrict__ A,
                                              const _Float16* __restrict__ Wt,
                                              const float* __restrict__ bias,
                                              _Float16* __restrict__ C) {
  __shared__ __align__(16) _Float16 As[128 * 32];
  __shared__ __align__(16) _Float16 Bs[128 * 32];
  const int tid = threadIdx.x;
  const int wv = tid >> 6, ln = tid & 63;
  const int wm = wv >> 1, wn = wv & 1;
  const int jl = ln & 15, q = ln >> 4;

  const int lid  = blockIdx.x + 400 * blockIdx.y;   // dispatch order
  const int xcd  = lid & 7;
  const int slot = lid >> 3;                        // 0..599
  const int mi   = xcd * 50 + (slot / 12);          // 0..399
  const int ni   = slot % 12;                       // 0..11
  const int m0 = mi * 128, n0 = ni * 128;

  const int r0 = tid >> 2, k80 = (tid & 3) * 8;
  const int r1 = r0 + 64;

  fx4 acc[4][4];
#pragma unroll
  for (int a = 0; a < 4; ++a)
#pragma unroll
    for (int b = 0; b < 4; ++b) acc[a][b] = (fx4){0.f, 0.f, 0.f, 0.f};

  for (int kk = 0; kk < KDIM; kk += 32) {
    gload_lds16(A  + (size_t)(m0 + r0) * KDIM + kk + k80, As + tid * 8);
    gload_lds16(A  + (size_t)(m0 + r1) * KDIM + kk + k80, As + (tid + 256) * 8);
    gload_lds16(Wt + (size_t)(n0 + r0) * KDIM + kk + k80, Bs + tid * 8);
    gload_lds16(Wt + (size_t)(n0 + r1) * KDIM + kk + k80, Bs + (tid + 256) * 8);
    __syncthreads();
    half8 af[4], bfr[4];
#pragma unroll
    for (int mt = 0; mt < 4; ++mt)
      af[mt] = *(const half8*)(As + (wm * 64 + mt * 16 + jl) * 32 + q * 8);
#pragma unroll
    for (int nt = 0; nt < 4; ++nt)
      bfr[nt] = *(const half8*)(Bs + (wn * 64 + nt * 16 + jl) * 32 + q * 8);
#pragma unroll
    for (int mt = 0; mt < 4; ++mt)
#pragma unroll
      for (int nt = 0; nt < 4; ++nt)
        acc[mt][nt] = __builtin_amdgcn_mfma_f32_16x16x32_f16(af[mt], bfr[nt], acc[mt][nt], 0, 0, 0);
    __syncthreads();
  }

  float bsv[4];
#pragma unroll
  for (int nt = 0; nt < 4; ++nt) bsv[nt] = bias[n0 + wn * 64 + nt * 16 + jl];

  // direct paired store: global col = n0 + wn*64 + ntp*32 + jl*2 + {0,1}
#pragma unroll
  for (int mt = 0; mt < 4; ++mt) {
#pragma unroll
    for (int ntp = 0; ntp < 2; ++ntp) {
#pragma unroll
      for (int rg = 0; rg < 4; ++rg) {
        const int grow = m0 + wm * 64 + mt * 16 + q * 4 + rg;
        _Float16 lo = (_Float16)(acc[mt][2 * ntp][rg]     + bsv[2 * ntp]);
        _Float16 hi = (_Float16)(acc[mt][2 * ntp + 1][rg] + bsv[2 * ntp + 1]);
        unsigned pk = (unsigned)__builtin_bit_cast(unsigned short, lo)
                    | ((unsigned)__builtin_bit_cast(unsigned short, hi) << 16);
        *(unsigned*)(C + (size_t)grow * NG + n0 + wn * 64 + ntp * 32 + jl * 2) = pk;
      }
    }
  }
}

// ---------------------------- GRU recurrence -------------------------------
// 32 blocks (16 batch-tiles x 2 dirs) x 512 threads (8 waves, 2/SIMD).
// Wave w owns hidden [32w, 32w+32) = 2 tiles. r,z weights pinned in VGPRs;
// n weights in LDS. h: LDS double-buffer, XOR chunk swizzle; hprev in regs;
// xi folded into acc init; custom lgkm-only barrier.
// R12: xi in paired layout -> 12 dword loads/thread/step (was 24 ushort).
// FROZEN since R14 (362us verified). Do NOT unroll the t-loop or remove the
// cx<-nx copies (R7: fence placement). Do NOT pin more weights (R11: spill).
__global__ __launch_bounds__(512) __attribute__((amdgpu_waves_per_eu(2, 2)))
void k_gru(const _Float16* __restrict__ xi,
           const _Float16* __restrict__ whp,
           const float* __restrict__ bhhf,
           const float* __restrict__ bhhr,
           _Float16* __restrict__ out) {
  extern __shared__ _Float16 smem[];
  _Float16* nlds = smem;                  // 16*8*512 = 65536 halves (128 KB)
  _Float16* hb0  = smem + 65536;          // 16 rows * 256 = 4096
  _Float16* hb1  = smem + 69632;          // 4096  -> total 147456 B

  const int tid = threadIdx.x, w = tid >> 6, ln = tid & 63;
  const int jl = ln & 15, q = ln >> 4;
  const int bt = blockIdx.x, dir = blockIdx.y;
  const float* bhh = dir ? bhhr : bhhf;

  // ---- weights: r,z pinned VGPR; n -> LDS ----
  half8 wrz[2][2][8];   // [tile][gate r/z][kf] = 32 half8 = 128 VGPRs
#pragma unroll
  for (int tt = 0; tt < 2; ++tt) {
    const _Float16* wb = whp + ((size_t)(dir * 16 + w * 2 + tt)) * 12288;
#pragma unroll
    for (int g = 0; g < 2; ++g)
#pragma unroll
      for (int kf = 0; kf < 8; ++kf) {
        wrz[tt][g][kf] = *(const half8*)(wb + g * 4096 + kf * 512 + ln * 8);
        asm volatile("" : "+v"(wrz[tt][g][kf]));   // pin: opaque def, no remat
      }
#pragma unroll
    for (int kf = 0; kf < 8; ++kf)
      *(half8*)(nlds + ((w * 2 + tt) * 8 + kf) * 512 + ln * 8) =
          *(const half8*)(wb + 2 * 4096 + kf * 512 + ln * 8);
  }
  float bhn[2];
#pragma unroll
  for (int tt = 0; tt < 2; ++tt) bhn[tt] = bhh[512 + w * 32 + tt * 16 + jl];

  for (int i = tid; i < 4096; i += 512) hb0[i] = (_Float16)0.f;

  // ---- xi pointers (per batch-row rg) + preload t0 (paired layout) ----
  const long long t0 = dir ? (SEQ - 1) : 0;
  const int xstep = dir ? -NG : NG;
  const int wcol2 = w * 32 + jl * 2;      // paired: tt in low/high half of dword
  const _Float16* xp[4];
#pragma unroll
  for (int rg = 0; rg < 4; ++rg)
    xp[rg] = xi + ((size_t)((bt * 16 + q * 4 + rg) * SEQ) + t0) * NG + dir * 768;

  unsigned cx[3][4];   // current step xi [gate][rg]; lo16 = tt0, hi16 = tt1
#pragma unroll
  for (int rg = 0; rg < 4; ++rg)
#pragma unroll
    for (int g = 0; g < 3; ++g)
      cx[g][rg] = *(const unsigned*)(xp[rg] + g * 256 + wcol2);

  // ---- coalesced out-store mapping (1 step delayed) ----
  const int orow = tid >> 5, oc = tid & 31;
  _Float16* op = out + ((size_t)((bt * 16 + orow) * SEQ) + t0) * 512 + dir * 256 + oc * 8;
  const int ostep = dir ? -512 : 512;
  const int oaddr = orow * 256 + ((oc ^ (orow & 7)) << 3);   // swizzled LDS src

  float hprev[2][4] = {{0.f,0.f,0.f,0.f},{0.f,0.f,0.f,0.f}};
  __syncthreads();   // nlds + hb0 ready (full barrier once)

  for (int t = 0; t < SEQ; ++t) {
    const _Float16* hr = (t & 1) ? hb1 : hb0;
    _Float16*       hw = (t & 1) ? hb0 : hb1;

    // prefetch xi(t+1) into regs; stays in flight across gru_barrier
    unsigned nx[3][4];
    if (t < SEQ - 1) {
#pragma unroll
      for (int rg = 0; rg < 4; ++rg) {
        const _Float16* p = xp[rg] + xstep;
#pragma unroll
        for (int g = 0; g < 3; ++g)
          nx[g][rg] = *(const unsigned*)(p + g * 256 + wcol2);
      }
    }

    // acc init: r/z = xi (has all biases), n = bhh_n (xi_n added in epilogue)
    fx4 acc[2][3];
#pragma unroll
    for (int rg = 0; rg < 4; ++rg) {
      const unsigned c0 = cx[0][rg], c1 = cx[1][rg];
      acc[0][0][rg] = lo16f(c0);
      acc[1][0][rg] = hi16f(c0);
      acc[0][1][rg] = lo16f(c1);
      acc[1][1][rg] = hi16f(c1);
      acc[0][2][rg] = bhn[0];
      acc[1][2][rg] = bhn[1];
    }

    // store h(t-1) to global (hr holds h(t-1))
    if (t > 0) {
      *(half8*)op = *(const half8*)(hr + oaddr);
      op += ostep;
    }

#pragma unroll
    for (int kf = 0; kf < 8; ++kf) {
      int cc = kf * 4 + q;                 // k-chunk 0..31
      half8 a = *(const half8*)(hr + jl * 256 + ((cc ^ (jl & 7)) << 3));
      half8 nb0 = *(const half8*)(nlds + ((w * 2 + 0) * 8 + kf) * 512 + ln * 8);
      half8 nb1 = *(const half8*)(nlds + ((w * 2 + 1) * 8 + kf) * 512 + ln * 8);
      acc[0][0] = __builtin_amdgcn_mfma_f32_16x16x32_f16(a, wrz[0][0][kf], acc[0][0], 0, 0, 0);
      acc[0][1] = __builtin_amdgcn_mfma_f32_16x16x32_f16(a, wrz[0][1][kf], acc[0][1], 0, 0, 0);
      acc[0][2] = __builtin_amdgcn_mfma_f32_16x16x32_f16(a, nb0,           acc[0][2], 0, 0, 0);
      acc[1][0] = __builtin_amdgcn_mfma_f32_16x16x32_f16(a, wrz[1][0][kf], acc[1][0], 0, 0, 0);
      acc[1][1] = __builtin_amdgcn_mfma_f32_16x16x32_f16(a, wrz[1][1][kf], acc[1][1], 0, 0, 0);
      acc[1][2] = __builtin_amdgcn_mfma_f32_16x16x32_f16(a, nb1,           acc[1][2], 0, 0, 0);
    }

#pragma unroll
    for (int tt = 0; tt < 2; ++tt) {
      const int col = w * 32 + jl + tt * 16;
      const int chunk = col >> 3;
#pragma unroll
      for (int rg = 0; rg < 4; ++rg) {
        const int rr = q * 4 + rg;
        const int haddr = rr * 256 + ((chunk ^ (rr & 7)) << 3) + (jl & 7);
        float xn = tt ? hi16f(cx[2][rg]) : lo16f(cx[2][rg]);
        float rv = __builtin_amdgcn_rcpf(1.f + __expf(-acc[tt][0][rg]));
        float zv = __builtin_amdgcn_rcpf(1.f + __expf(-acc[tt][1][rg]));
        float gn = fmaf(rv, acc[tt][2][rg], xn);
        float e2 = __expf(2.f * gn);
        float nn = fmaf(-2.f, __builtin_amdgcn_rcpf(e2 + 1.f), 1.f);  // tanh
        float hp = hprev[tt][rg];
        float h = fmaf(zv, hp - nn, nn);
        hprev[tt][rg] = h;
        hw[haddr] = (_Float16)h;
      }
    }
#pragma unroll
    for (int rg = 0; rg < 4; ++rg) {
      xp[rg] += (t < SEQ - 1) ? xstep : 0;
#pragma unroll
      for (int g = 0; g < 3; ++g) cx[g][rg] = nx[g][rg];
    }
    gru_barrier();   // lgkm-only: h(t) visible, xi prefetch stays in flight
  }
  // flush h(SEQ-1): written at t=199 into hb0
  *(half8*)op = *(const half8*)(hb0 + oaddr);
}

// ---------------------------- heads ----------------------------------------

// 3200 blocks x 256 thr; each wave handles 4 (b,t) rows, fc weights cached in
// per-thread registers (cols ln*8..ln*8+7) -> 4x less L2 broadcast traffic.
__global__ __launch_bounds__(256) void k_heads1(const _Float16* __restrict__ out,
                                                const float* __restrict__ fc1w,
                                                const float* __restrict__ fc1b,
                                                const float* __restrict__ fc2w,
                                                const float* __restrict__ fc2b,
                                                float* __restrict__ y,
                                                float* __restrict__ y2) {
  const int tid = threadIdx.x, wv = tid >> 6, ln = tid & 63;

  float4 w1a = *(const float4*)(fc1w + ln * 8);
  float4 w1b = *(const float4*)(fc1w + ln * 8 + 4);
  float4 wa[10], wb[10];
#pragma unroll
  for (int c = 0; c < 10; ++c) {
    wa[c] = *(const float4*)(fc2w + c * 512 + ln * 8);
    wb[c] = *(const float4*)(fc2w + c * 512 + ln * 8 + 4);
  }
  float b1 = fc1b[0];
  float b2[10];
#pragma unroll
  for (int c = 0; c < 10; ++c) b2[c] = fc2b[c];

#pragma unroll
  for (int i = 0; i < 4; ++i) {
    int gw = blockIdx.x * 16 + wv * 4 + i;
    int b = gw / SEQ, t = gw - b * SEQ;
    half8 ov = *(const half8*)(out + (size_t)gw * 512 + ln * 8);
    float o[8];
#pragma unroll
    for (int k = 0; k < 8; ++k) o[k] = (float)ov[k];

    float s1 = o[0]*w1a.x + o[1]*w1a.y + o[2]*w1a.z + o[3]*w1a.w
             + o[4]*w1b.x + o[5]*w1b.y + o[6]*w1b.z + o[7]*w1b.w;
    float s2[10];
#pragma unroll
    for (int c = 0; c < 10; ++c) {
      s2[c] = o[0]*wa[c].x + o[1]*wa[c].y + o[2]*wa[c].z + o[3]*wa[c].w
            + o[4]*wb[c].x + o[5]*wb[c].y + o[6]*wb[c].z + o[7]*wb[c].w;
    }
#pragma unroll
    for (int m = 32; m; m >>= 1) {
      s1 += __shfl_xor(s1, m);
#pragma unroll
      for (int c = 0; c < 10; ++c) s2[c] += __shfl_xor(s2[c], m);
    }
    if (ln == 0) {
      y[gw] = s1 + b1;
      float* y2p = y2 + (size_t)b * 2000 + t * 10;
#pragma unroll
      for (int c = 0; c < 10; ++c) y2p[c] = s2[c] + b2[c];
    }
  }
}

__device__ __forceinline__ float blkRedMax(float v, float* red, int tid) {
#pragma unroll
  for (int m = 32; m; m >>= 1) v = fmaxf(v, __shfl_xor(v, m));
  __syncthreads();
  if ((tid & 63) == 0) red[tid >> 6] = v;
  __syncthreads();
  return fmaxf(fmaxf(red[0], red[1]), fmaxf(red[2], red[3]));
}
__device__ __forceinline__ float blkRedSum(float v, float* red, int tid) {
#pragma unroll
  for (int m = 32; m; m >>= 1) v += __shfl_xor(v, m);
  __syncthreads();
  if ((tid & 63) == 0) red[tid >> 6] = v;
  __syncthreads();
  return red[0] + red[1] + red[2] + red[3];
}

__global__ __launch_bounds__(256) void k_heads2(const float* __restrict__ y,
                                                const float* __restrict__ y2,
                                                float* __restrict__ y3) {
  __shared__ float sp[SEQ];
  __shared__ float se[2000];
  __shared__ float red[4];
  int b = blockIdx.x, tid = threadIdx.x;

  float v = (tid < SEQ) ? y[(size_t)b * SEQ + tid] : -3.0e38f;
  float mx = blkRedMax(v, red, tid);
  float e = (tid < SEQ) ? __expf(v - mx) : 0.f;
  float sum = blkRedSum(e, red, tid);
  if (tid < SEQ) sp[tid] = e / (sum * 10.f);

  float vv[8];
  float lm = -3.0e38f;
#pragma unroll
  for (int r = 0; r < 8; ++r) {
    int k = tid + r * 256;
    vv[r] = (k < 2000) ? y2[(size_t)b * 2000 + k] : -3.0e38f;
    lm = fmaxf(lm, vv[r]);
  }
  float mx2 = blkRedMax(lm, red, tid);
  float ls = 0.f;
#pragma unroll
  for (int r = 0; r < 8; ++r) {
    int k = tid + r * 256;
    if (k < 2000) { float ee = __expf(vv[r] - mx2); se[k] = ee; ls += ee; }
  }
  float sum2 = blkRedSum(ls, red, tid);
  __syncthreads();
  float inv = 1.f / sum2;
#pragma unroll
  for (int r = 0; r < 8; ++r) {
    int k = tid + r * 256;
    if (k < 2000) y3[(size_t)b * 2000 + k] = se[k] * inv + sp[k / 10];
  }
}

// ---------------------------- launch ---------------------------------------

extern "C" void kernel_launch(void* const* d_in, const int* in_sizes, int n_in,
                              void* d_out, int out_size, void* d_ws, size_t ws_size,
                              hipStream_t stream) {
  const float* x     = (const float*)d_in[0];
  const float* wih0  = (const float*)d_in[1];
  const float* whh0  = (const float*)d_in[2];
  const float* bih0  = (const float*)d_in[3];
  const float* bhh0  = (const float*)d_in[4];
  const float* wih0r = (const float*)d_in[5];
  const float* whh0r = (const float*)d_in[6];
  const float* bih0r = (const float*)d_in[7];
  const float* bhh0r = (const float*)d_in[8];
  const float* wih1  = (const float*)d_in[9];
  const float* whh1  = (const float*)d_in[10];
  const float* bih1  = (const float*)d_in[11];
  const float* bhh1  = (const float*)d_in[12];
  const float* wih1r = (const float*)d_in[13];
  const float* whh1r = (const float*)d_in[14];
  const float* bih1r = (const float*)d_in[15];
  const float* bhh1r = (const float*)d_in[16];
  const float* fc1w  = (const float*)d_in[17];
  const float* fc1b  = (const float*)d_in[18];
  const float* fc2w  = (const float*)d_in[19];
  const float* fc2b  = (const float*)d_in[20];

  char* ws = (char*)d_ws;
  _Float16* xh    = (_Float16*)(ws + 0);
  _Float16* xi    = (_Float16*)(ws + 52428800);
  _Float16* l0    = (_Float16*)(ws + 209715200);
  _Float16* outh  = (_Float16*)(ws + 262144000);
  _Float16* wcat0 = (_Float16*)(ws + 314572800);
  _Float16* wcat1 = (_Float16*)(ws + 316145664);
  _Float16* whp0  = (_Float16*)(ws + 317718528);
  _Float16* whp1  = (_Float16*)(ws + 318504960);
  float*    bcat0 = (float*)(ws + 319291392);
  float*    bcat1 = (float*)(ws + 319297536);

  float* y  = (float*)d_out;
  float* y2 = (float*)d_out + 51200;
  float* y3 = (float*)d_out + 563200;

  k_cast_x<<<25600, 256, 0, stream>>>((const float4*)x, (half4v*)xh, 6553600);
  k_prep_wih<<<3072, 256, 0, stream>>>(wih0, wih0r, bih0, bih0r, bhh0, bhh0r, wcat0, bcat0);
  k_prep_wih<<<3072, 256, 0, stream>>>(wih1, wih1r, bih1, bih1r, bhh1, bhh1r, wcat1, bcat1);
  k_prep_whh<<<1536, 256, 0, stream>>>(whh0, whh0r, whp0);
  k_prep_whh<<<1536, 256, 0, stream>>>(whh1, whh1r, whp1);

  hipFuncSetAttribute(reinterpret_cast<const void*>(k_gru),
                      hipFuncAttributeMaxDynamicSharedMemorySize, 147456);

  k_gemm<<<dim3(400, 12), 256, 0, stream>>>(xh, wcat0, bcat0, xi);
  k_gru<<<dim3(16, 2), 512, 147456, stream>>>(xi, whp0, bhh0, bhh0r, l0);
  k_gemm<<<dim3(400, 12), 256, 0, stream>>>(l0, wcat1, bcat1, xi);
  k_gru<<<dim3(16, 2), 512, 147456, stream>>>(xi, whp1, bhh1, bhh1r, outh);
  k_heads1<<<3200, 256, 0, stream>>>(outh, fc1w, fc1b, fc2w, fc2b, y, y2);
  k_heads2<<<256, 256, 0, stream>>>(y, y2, y3);
}

// Round 10
// 1136.032 us; speedup vs baseline: 4.7273x; 1.0179x over previous
//
#include <hip/hip_runtime.h>

// ---------------------------------------------------------------------------
// Bidirectional 2-layer GRU (B=256, L=200, IN=512, H=256) + FC heads.
// R16: k_gru FROZEN (R14, 362-364us verified). Changes:
//  - k_gemm BK=32 -> BK=64: halves per-block barrier-drain events (16->8),
//    the documented 2-phase critical path (m233: stage+vmcnt+barrier ~72%).
//    LDS 32KB (2x 128x64 fp16), ~3 blocks/CU preserved. Row stride 128B
//    would be a 16-way ds_read conflict -> both-sides XOR chunk swizzle:
//    LDS(r,c) holds global k-chunk c^(r&7) (pre-swizzled SOURCE, linear
//    gload_lds dest); reader XORs the same way. Epilogue = R15 direct
//    paired-dword store (verified neutral, kept for simplicity).
//  - 4 prep kernels merged into 1 launch (-3 launches).
//  History: R15 epilogue-deLDS = neutral (epilogue not on critical path).
//  R14 paired-xi = -41us/gru. R11 full-pin = spill (dead). R9/R10
//  cross-block sync = dead. R7 t-unroll = fence regression (dead).
// ---------------------------------------------------------------------------

typedef _Float16 half8 __attribute__((ext_vector_type(8)));
typedef _Float16 half4v __attribute__((ext_vector_type(4)));
typedef float fx4 __attribute__((ext_vector_type(4)));

#define BATCH 256
#define SEQ   200
#define HID   256
#define MROWS (BATCH*SEQ)   // 51200
#define NG    1536          // 3H * 2 directions
#define KDIM  512

__device__ __forceinline__ void gload_lds16(const _Float16* g, _Float16* l) {
  __builtin_amdgcn_global_load_lds((const __attribute__((address_space(1))) void*)g,
                                   (__attribute__((address_space(3))) void*)l, 16, 0, 0);
}

// Barrier that drains only LDS ops (lgkmcnt), NOT vmcnt: global prefetch
// loads stay outstanding across the step boundary.
__device__ __forceinline__ void gru_barrier() {
  asm volatile("s_waitcnt lgkmcnt(0)\n\ts_barrier" ::: "memory");
}

__device__ __forceinline__ float lo16f(unsigned v) {
  return (float)__builtin_bit_cast(_Float16, (unsigned short)(v & 0xffffu));
}
__device__ __forceinline__ float hi16f(unsigned v) {
  return (float)__builtin_bit_cast(_Float16, (unsigned short)(v >> 16));
}

// ---------------------------- prep kernels ---------------------------------

__global__ __launch_bounds__(256) void k_cast_x(const float4* __restrict__ x,
                                                half4v* __restrict__ xh, int n4) {
  int i = blockIdx.x * 256 + threadIdx.x;
  if (i < n4) {
    float4 v = x[i];
    half4v o;
    o[0] = (_Float16)v.x; o[1] = (_Float16)v.y; o[2] = (_Float16)v.z; o[3] = (_Float16)v.w;
    xh[i] = o;
  }
}

__device__ __forceinline__ void prep_wih_body(int idx,
    const float* wf, const float* wr, const float* bf_, const float* br_,
    const float* bhf, const float* bhr, _Float16* wcat, float* bcat) {
  int n = idx >> 9;
  float v = (n < 768) ? wf[idx] : wr[idx - 768 * 512];
  wcat[idx] = (_Float16)v;
  if (idx < 1536) {
    float b;
    if (idx < 768) b = bf_[idx] + ((idx < 512) ? bhf[idx] : 0.f);
    else { int i2 = idx - 768; b = br_[i2] + ((i2 < 512) ? bhr[i2] : 0.f); }
    bcat[idx] = b;
  }
}

__device__ __forceinline__ void prep_whh_body(int e,
    const float* whf, const float* whr, _Float16* whp) {
  int dir = e / 196608;
  int r = e - dir * 196608;
  int w = r / 12288;  int r2 = r - w * 12288;
  int gate = r2 >> 12; int r3 = r2 & 4095;
  int kf = r3 >> 9;    int r4 = r3 & 511;
  int lane = r4 >> 3;  int i = r4 & 7;
  int row = gate * 256 + w * 16 + (lane & 15);
  int col = kf * 32 + (lane >> 4) * 8 + i;
  const float* src = dir ? whr : whf;
  whp[e] = (_Float16)src[row * 256 + col];
}

// All 4 weight-prep jobs in one launch: blocks [0,3072) wih0, [3072,6144)
// wih1, [6144,7680) whh0, [7680,9216) whh1.
__global__ __launch_bounds__(256) void k_prep_all(
    const float* __restrict__ wih0, const float* __restrict__ wih0r,
    const float* __restrict__ bih0, const float* __restrict__ bih0r,
    const float* __restrict__ bhh0, const float* __restrict__ bhh0r,
    _Float16* __restrict__ wcat0, float* __restrict__ bcat0,
    const float* __restrict__ wih1, const float* __restrict__ wih1r,
    const float* __restrict__ bih1, const float* __restrict__ bih1r,
    const float* __restrict__ bhh1, const float* __restrict__ bhh1r,
    _Float16* __restrict__ wcat1, float* __restrict__ bcat1,
    const float* __restrict__ whh0, const float* __restrict__ whh0r,
    _Float16* __restrict__ whp0,
    const float* __restrict__ whh1, const float* __restrict__ whh1r,
    _Float16* __restrict__ whp1) {
  const int b = blockIdx.x, tid = threadIdx.x;
  if (b < 3072) {
    prep_wih_body(b * 256 + tid, wih0, wih0r, bih0, bih0r, bhh0, bhh0r, wcat0, bcat0);
  } else if (b < 6144) {
    prep_wih_body((b - 3072) * 256 + tid, wih1, wih1r, bih1, bih1r, bhh1, bhh1r, wcat1, bcat1);
  } else if (b < 7680) {
    prep_whh_body((b - 6144) * 256 + tid, whh0, whh0r, whp0);
  } else {
    prep_whh_body((b - 7680) * 256 + tid, whh1, whh1r, whp1);
  }
}

// ---------------------------- xi GEMM --------------------------------------
// m97 2-phase structure, BK=64 (R16): 8 K-iters/block, 2 barriers each.
// XCD-aware remap (R7): 12 N-blocks sharing an A-tile run consecutively on
// one XCD. LDS tiles 128x64 fp16 with chunk-XOR swizzle: LDS(r,c8) holds
// global k-chunk (c8 ^ (r&7)); gload_lds dest linear, SOURCE pre-swizzled,
// reads XOR the same way (both-sides rule). C stored in R12 PAIRED layout
// via R15 direct packed-dword stores.
__global__ __launch_bounds__(256) void k_gemm(const _Float16* __restrict__ A,
                                              const _Float16* __restrict__ Wt,
                                              const float* __restrict__ bias,
                                              _Float16* __restrict__ C) {
  __shared__ __align__(16) _Float16 As[128 * 64];
  __shared__ __align__(16) _Float16 Bs[128 * 64];
  const int tid = threadIdx.x;
  const int wv = tid >> 6, ln = tid & 63;
  const int wm = wv >> 1, wn = wv & 1;
  const int jl = ln & 15, q = ln >> 4;

  const int lid  = blockIdx.x + 400 * blockIdx.y;   // dispatch order
  const int xcd  = lid & 7;
  const int slot = lid >> 3;                        // 0..599
  const int mi   = xcd * 50 + (slot / 12);          // 0..399
  const int ni   = slot % 12;                       // 0..11
  const int m0 = mi * 128, n0 = ni * 128;

  fx4 acc[4][4];
#pragma unroll
  for (int a = 0; a < 4; ++a)
#pragma unroll
    for (int b = 0; b < 4; ++b) acc[a][b] = (fx4){0.f, 0.f, 0.f, 0.f};

  // staging: 1024 chunks of 16B per tile; thread covers chunks tid+256*i
  for (int kk = 0; kk < KDIM; kk += 64) {
#pragma unroll
    for (int i = 0; i < 4; ++i) {
      const int ch = tid + 256 * i;
      const int r = ch >> 3, c = ch & 7;
      const int sc = ((c ^ (r & 7)) << 3);          // swizzled source k-offset
      gload_lds16(A  + (size_t)(m0 + r) * KDIM + kk + sc, As + ch * 8);
      gload_lds16(Wt + (size_t)(n0 + r) * KDIM + kk + sc, Bs + ch * 8);
    }
    __syncthreads();
    half8 af[2][4], bfr[2][4];
#pragma unroll
    for (int kh = 0; kh < 2; ++kh) {
      const int wc = kh * 4 + q;                    // wanted k-chunk 0..7
#pragma unroll
      for (int mt = 0; mt < 4; ++mt) {
        const int row = wm * 64 + mt * 16 + jl;
        af[kh][mt] = *(const half8*)(As + row * 64 + ((wc ^ (row & 7)) << 3));
      }
#pragma unroll
      for (int nt = 0; nt < 4; ++nt) {
        const int row = wn * 64 + nt * 16 + jl;
        bfr[kh][nt] = *(const half8*)(Bs + row * 64 + ((wc ^ (row & 7)) << 3));
      }
    }
#pragma unroll
    for (int kh = 0; kh < 2; ++kh)
#pragma unroll
      for (int mt = 0; mt < 4; ++mt)
#pragma unroll
        for (int nt = 0; nt < 4; ++nt)
          acc[mt][nt] = __builtin_amdgcn_mfma_f32_16x16x32_f16(af[kh][mt], bfr[kh][nt], acc[mt][nt], 0, 0, 0);
    __syncthreads();
  }

  float bsv[4];
#pragma unroll
  for (int nt = 0; nt < 4; ++nt) bsv[nt] = bias[n0 + wn * 64 + nt * 16 + jl];

  // direct paired store: global col = n0 + wn*64 + ntp*32 + jl*2 + {0,1}
#pragma unroll
  for (int mt = 0; mt < 4; ++mt) {
#pragma unroll
    for (int ntp = 0; ntp < 2; ++ntp) {
#pragma unroll
      for (int rg = 0; rg < 4; ++rg) {
        const int grow = m0 + wm * 64 + mt * 16 + q * 4 + rg;
        _Float16 lo = (_Float16)(acc[mt][2 * ntp][rg]     + bsv[2 * ntp]);
        _Float16 hi = (_Float16)(acc[mt][2 * ntp + 1][rg] + bsv[2 * ntp + 1]);
        unsigned pk = (unsigned)__builtin_bit_cast(unsigned short, lo)
                    | ((unsigned)__builtin_bit_cast(unsigned short, hi) << 16);
        *(unsigned*)(C + (size_t)grow * NG + n0 + wn * 64 + ntp * 32 + jl * 2) = pk;
      }
    }
  }
}

// ---------------------------- GRU recurrence -------------------------------
// 32 blocks (16 batch-tiles x 2 dirs) x 512 threads (8 waves, 2/SIMD).
// Wave w owns hidden [32w, 32w+32) = 2 tiles. r,z weights pinned in VGPRs;
// n weights in LDS. h: LDS double-buffer, XOR chunk swizzle; hprev in regs;
// xi folded into acc init; custom lgkm-only barrier.
// R12: xi in paired layout -> 12 dword loads/thread/step (was 24 ushort).
// FROZEN since R14 (362us verified). Do NOT unroll the t-loop or remove the
// cx<-nx copies (R7: fence placement). Do NOT pin more weights (R11: spill).
__global__ __launch_bounds__(512) __attribute__((amdgpu_waves_per_eu(2, 2)))
void k_gru(const _Float16* __restrict__ xi,
           const _Float16* __restrict__ whp,
           const float* __restrict__ bhhf,
           const float* __restrict__ bhhr,
           _Float16* __restrict__ out) {
  extern __shared__ _Float16 smem[];
  _Float16* nlds = smem;                  // 16*8*512 = 65536 halves (128 KB)
  _Float16* hb0  = smem + 65536;          // 16 rows * 256 = 4096
  _Float16* hb1  = smem + 69632;          // 4096  -> total 147456 B

  const int tid = threadIdx.x, w = tid >> 6, ln = tid & 63;
  const int jl = ln & 15, q = ln >> 4;
  const int bt = blockIdx.x, dir = blockIdx.y;
  const float* bhh = dir ? bhhr : bhhf;

  // ---- weights: r,z pinned VGPR; n -> LDS ----
  half8 wrz[2][2][8];   // [tile][gate r/z][kf] = 32 half8 = 128 VGPRs
#pragma unroll
  for (int tt = 0; tt < 2; ++tt) {
    const _Float16* wb = whp + ((size_t)(dir * 16 + w * 2 + tt)) * 12288;
#pragma unroll
    for (int g = 0; g < 2; ++g)
#pragma unroll
      for (int kf = 0; kf < 8; ++kf) {
        wrz[tt][g][kf] = *(const half8*)(wb + g * 4096 + kf * 512 + ln * 8);
        asm volatile("" : "+v"(wrz[tt][g][kf]));   // pin: opaque def, no remat
      }
#pragma unroll
    for (int kf = 0; kf < 8; ++kf)
      *(half8*)(nlds + ((w * 2 + tt) * 8 + kf) * 512 + ln * 8) =
          *(const half8*)(wb + 2 * 4096 + kf * 512 + ln * 8);
  }
  float bhn[2];
#pragma unroll
  for (int tt = 0; tt < 2; ++tt) bhn[tt] = bhh[512 + w * 32 + tt * 16 + jl];

  for (int i = tid; i < 4096; i += 512) hb0[i] = (_Float16)0.f;

  // ---- xi pointers (per batch-row rg) + preload t0 (paired layout) ----
  const long long t0 = dir ? (SEQ - 1) : 0;
  const int xstep = dir ? -NG : NG;
  const int wcol2 = w * 32 + jl * 2;      // paired: tt in low/high half of dword
  const _Float16* xp[4];
#pragma unroll
  for (int rg = 0; rg < 4; ++rg)
    xp[rg] = xi + ((size_t)((bt * 16 + q * 4 + rg) * SEQ) + t0) * NG + dir * 768;

  unsigned cx[3][4];   // current step xi [gate][rg]; lo16 = tt0, hi16 = tt1
#pragma unroll
  for (int rg = 0; rg < 4; ++rg)
#pragma unroll
    for (int g = 0; g < 3; ++g)
      cx[g][rg] = *(const unsigned*)(xp[rg] + g * 256 + wcol2);

  // ---- coalesced out-store mapping (1 step delayed) ----
  const int orow = tid >> 5, oc = tid & 31;
  _Float16* op = out + ((size_t)((bt * 16 + orow) * SEQ) + t0) * 512 + dir * 256 + oc * 8;
  const int ostep = dir ? -512 : 512;
  const int oaddr = orow * 256 + ((oc ^ (orow & 7)) << 3);   // swizzled LDS src

  float hprev[2][4] = {{0.f,0.f,0.f,0.f},{0.f,0.f,0.f,0.f}};
  __syncthreads();   // nlds + hb0 ready (full barrier once)

  for (int t = 0; t < SEQ; ++t) {
    const _Float16* hr = (t & 1) ? hb1 : hb0;
    _Float16*       hw = (t & 1) ? hb0 : hb1;

    // prefetch xi(t+1) into regs; stays in flight across gru_barrier
    unsigned nx[3][4];
    if (t < SEQ - 1) {
#pragma unroll
      for (int rg = 0; rg < 4; ++rg) {
        const _Float16* p = xp[rg] + xstep;
#pragma unroll
        for (int g = 0; g < 3; ++g)
          nx[g][rg] = *(const unsigned*)(p + g * 256 + wcol2);
      }
    }

    // acc init: r/z = xi (has all biases), n = bhh_n (xi_n added in epilogue)
    fx4 acc[2][3];
#pragma unroll
    for (int rg = 0; rg < 4; ++rg) {
      const unsigned c0 = cx[0][rg], c1 = cx[1][rg];
      acc[0][0][rg] = lo16f(c0);
      acc[1][0][rg] = hi16f(c0);
      acc[0][1][rg] = lo16f(c1);
      acc[1][1][rg] = hi16f(c1);
      acc[0][2][rg] = bhn[0];
      acc[1][2][rg] = bhn[1];
    }

    // store h(t-1) to global (hr holds h(t-1))
    if (t > 0) {
      *(half8*)op = *(const half8*)(hr + oaddr);
      op += ostep;
    }

#pragma unroll
    for (int kf = 0; kf < 8; ++kf) {
      int cc = kf * 4 + q;                 // k-chunk 0..31
      half8 a = *(const half8*)(hr + jl * 256 + ((cc ^ (jl & 7)) << 3));
      half8 nb0 = *(const half8*)(nlds + ((w * 2 + 0) * 8 + kf) * 512 + ln * 8);
      half8 nb1 = *(const half8*)(nlds + ((w * 2 + 1) * 8 + kf) * 512 + ln * 8);
      acc[0][0] = __builtin_amdgcn_mfma_f32_16x16x32_f16(a, wrz[0][0][kf], acc[0][0], 0, 0, 0);
      acc[0][1] = __builtin_amdgcn_mfma_f32_16x16x32_f16(a, wrz[0][1][kf], acc[0][1], 0, 0, 0);
      acc[0][2] = __builtin_amdgcn_mfma_f32_16x16x32_f16(a, nb0,           acc[0][2], 0, 0, 0);
      acc[1][0] = __builtin_amdgcn_mfma_f32_16x16x32_f16(a, wrz[1][0][kf], acc[1][0], 0, 0, 0);
      acc[1][1] = __builtin_amdgcn_mfma_f32_16x16x32_f16(a, wrz[1][1][kf], acc[1][1], 0, 0, 0);
      acc[1][2] = __builtin_amdgcn_mfma_f32_16x16x32_f16(a, nb1,           acc[1][2], 0, 0, 0);
    }

#pragma unroll
    for (int tt = 0; tt < 2; ++tt) {
      const int col = w * 32 + jl + tt * 16;
      const int chunk = col >> 3;
#pragma unroll
      for (int rg = 0; rg < 4; ++rg) {
        const int rr = q * 4 + rg;
        const int haddr = rr * 256 + ((chunk ^ (rr & 7)) << 3) + (jl & 7);
        float xn = tt ? hi16f(cx[2][rg]) : lo16f(cx[2][rg]);
        float rv = __builtin_amdgcn_rcpf(1.f + __expf(-acc[tt][0][rg]));
        float zv = __builtin_amdgcn_rcpf(1.f + __expf(-acc[tt][1][rg]));
        float gn = fmaf(rv, acc[tt][2][rg], xn);
        float e2 = __expf(2.f * gn);
        float nn = fmaf(-2.f, __builtin_amdgcn_rcpf(e2 + 1.f), 1.f);  // tanh
        float hp = hprev[tt][rg];
        float h = fmaf(zv, hp - nn, nn);
        hprev[tt][rg] = h;
        hw[haddr] = (_Float16)h;
      }
    }
#pragma unroll
    for (int rg = 0; rg < 4; ++rg) {
      xp[rg] += (t < SEQ - 1) ? xstep : 0;
#pragma unroll
      for (int g = 0; g < 3; ++g) cx[g][rg] = nx[g][rg];
    }
    gru_barrier();   // lgkm-only: h(t) visible, xi prefetch stays in flight
  }
  // flush h(SEQ-1): written at t=199 into hb0
  *(half8*)op = *(const half8*)(hb0 + oaddr);
}

// ---------------------------- heads ----------------------------------------

// 3200 blocks x 256 thr; each wave handles 4 (b,t) rows, fc weights cached in
// per-thread registers (cols ln*8..ln*8+7) -> 4x less L2 broadcast traffic.
__global__ __launch_bounds__(256) void k_heads1(const _Float16* __restrict__ out,
                                                const float* __restrict__ fc1w,
                                                const float* __restrict__ fc1b,
                                                const float* __restrict__ fc2w,
                                                const float* __restrict__ fc2b,
                                                float* __restrict__ y,
                                                float* __restrict__ y2) {
  const int tid = threadIdx.x, wv = tid >> 6, ln = tid & 63;

  float4 w1a = *(const float4*)(fc1w + ln * 8);
  float4 w1b = *(const float4*)(fc1w + ln * 8 + 4);
  float4 wa[10], wb[10];
#pragma unroll
  for (int c = 0; c < 10; ++c) {
    wa[c] = *(const float4*)(fc2w + c * 512 + ln * 8);
    wb[c] = *(const float4*)(fc2w + c * 512 + ln * 8 + 4);
  }
  float b1 = fc1b[0];
  float b2[10];
#pragma unroll
  for (int c = 0; c < 10; ++c) b2[c] = fc2b[c];

#pragma unroll
  for (int i = 0; i < 4; ++i) {
    int gw = blockIdx.x * 16 + wv * 4 + i;
    int b = gw / SEQ, t = gw - b * SEQ;
    half8 ov = *(const half8*)(out + (size_t)gw * 512 + ln * 8);
    float o[8];
#pragma unroll
    for (int k = 0; k < 8; ++k) o[k] = (float)ov[k];

    float s1 = o[0]*w1a.x + o[1]*w1a.y + o[2]*w1a.z + o[3]*w1a.w
             + o[4]*w1b.x + o[5]*w1b.y + o[6]*w1b.z + o[7]*w1b.w;
    float s2[10];
#pragma unroll
    for (int c = 0; c < 10; ++c) {
      s2[c] = o[0]*wa[c].x + o[1]*wa[c].y + o[2]*wa[c].z + o[3]*wa[c].w
            + o[4]*wb[c].x + o[5]*wb[c].y + o[6]*wb[c].z + o[7]*wb[c].w;
    }
#pragma unroll
    for (int m = 32; m; m >>= 1) {
      s1 += __shfl_xor(s1, m);
#pragma unroll
      for (int c = 0; c < 10; ++c) s2[c] += __shfl_xor(s2[c], m);
    }
    if (ln == 0) {
      y[gw] = s1 + b1;
      float* y2p = y2 + (size_t)b * 2000 + t * 10;
#pragma unroll
      for (int c = 0; c < 10; ++c) y2p[c] = s2[c] + b2[c];
    }
  }
}

__device__ __forceinline__ float blkRedMax(float v, float* red, int tid) {
#pragma unroll
  for (int m = 32; m; m >>= 1) v = fmaxf(v, __shfl_xor(v, m));
  __syncthreads();
  if ((tid & 63) == 0) red[tid >> 6] = v;
  __syncthreads();
  return fmaxf(fmaxf(red[0], red[1]), fmaxf(red[2], red[3]));
}
__device__ __forceinline__ float blkRedSum(float v, float* red, int tid) {
#pragma unroll
  for (int m = 32; m; m >>= 1) v += __shfl_xor(v, m);
  __syncthreads();
  if ((tid & 63) == 0) red[tid >> 6] = v;
  __syncthreads();
  return red[0] + red[1] + red[2] + red[3];
}

__global__ __launch_bounds__(256) void k_heads2(const float* __restrict__ y,
                                                const float* __restrict__ y2,
                                                float* __restrict__ y3) {
  __shared__ float sp[SEQ];
  __shared__ float se[2000];
  __shared__ float red[4];
  int b = blockIdx.x, tid = threadIdx.x;

  float v = (tid < SEQ) ? y[(size_t)b * SEQ + tid] : -3.0e38f;
  float mx = blkRedMax(v, red, tid);
  float e = (tid < SEQ) ? __expf(v - mx) : 0.f;
  float sum = blkRedSum(e, red, tid);
  if (tid < SEQ) sp[tid] = e / (sum * 10.f);

  float vv[8];
  float lm = -3.0e38f;
#pragma unroll
  for (int r = 0; r < 8; ++r) {
    int k = tid + r * 256;
    vv[r] = (k < 2000) ? y2[(size_t)b * 2000 + k] : -3.0e38f;
    lm = fmaxf(lm, vv[r]);
  }
  float mx2 = blkRedMax(lm, red, tid);
  float ls = 0.f;
#pragma unroll
  for (int r = 0; r < 8; ++r) {
    int k = tid + r * 256;
    if (k < 2000) { float ee = __expf(vv[r] - mx2); se[k] = ee; ls += ee; }
  }
  float sum2 = blkRedSum(ls, red, tid);
  __syncthreads();
  float inv = 1.f / sum2;
#pragma unroll
  for (int r = 0; r < 8; ++r) {
    int k = tid + r * 256;
    if (k < 2000) y3[(size_t)b * 2000 + k] = se[k] * inv + sp[k / 10];
  }
}

// ---------------------------- launch ---------------------------------------

extern "C" void kernel_launch(void* const* d_in, const int* in_sizes, int n_in,
                              void* d_out, int out_size, void* d_ws, size_t ws_size,
                              hipStream_t stream) {
  const float* x     = (const float*)d_in[0];
  const float* wih0  = (const float*)d_in[1];
  const float* whh0  = (const float*)d_in[2];
  const float* bih0  = (const float*)d_in[3];
  const float* bhh0  = (const float*)d_in[4];
  const float* wih0r = (const float*)d_in[5];
  const float* whh0r = (const float*)d_in[6];
  const float* bih0r = (const float*)d_in[7];
  const float* bhh0r = (const float*)d_in[8];
  const float* wih1  = (const float*)d_in[9];
  const float* whh1  = (const float*)d_in[10];
  const float* bih1  = (const float*)d_in[11];
  const float* bhh1  = (const float*)d_in[12];
  const float* wih1r = (const float*)d_in[13];
  const float* whh1r = (const float*)d_in[14];
  const float* bih1r = (const float*)d_in[15];
  const float* bhh1r = (const float*)d_in[16];
  const float* fc1w  = (const float*)d_in[17];
  const float* fc1b  = (const float*)d_in[18];
  const float* fc2w  = (const float*)d_in[19];
  const float* fc2b  = (const float*)d_in[20];

  char* ws = (char*)d_ws;
  _Float16* xh    = (_Float16*)(ws + 0);
  _Float16* xi    = (_Float16*)(ws + 52428800);
  _Float16* l0    = (_Float16*)(ws + 209715200);
  _Float16* outh  = (_Float16*)(ws + 262144000);
  _Float16* wcat0 = (_Float16*)(ws + 314572800);
  _Float16* wcat1 = (_Float16*)(ws + 316145664);
  _Float16* whp0  = (_Float16*)(ws + 317718528);
  _Float16* whp1  = (_Float16*)(ws + 318504960);
  float*    bcat0 = (float*)(ws + 319291392);
  float*    bcat1 = (float*)(ws + 319297536);

  float* y  = (float*)d_out;
  float* y2 = (float*)d_out + 51200;
  float* y3 = (float*)d_out + 563200;

  k_cast_x<<<25600, 256, 0, stream>>>((const float4*)x, (half4v*)xh, 6553600);
  k_prep_all<<<9216, 256, 0, stream>>>(wih0, wih0r, bih0, bih0r, bhh0, bhh0r, wcat0, bcat0,
                                       wih1, wih1r, bih1, bih1r, bhh1, bhh1r, wcat1, bcat1,
                                       whh0, whh0r, whp0, whh1, whh1r, whp1);

  hipFuncSetAttribute(reinterpret_cast<const void*>(k_gru),
                      hipFuncAttributeMaxDynamicSharedMemorySize, 147456);

  k_gemm<<<dim3(400, 12), 256, 0, stream>>>(xh, wcat0, bcat0, xi);
  k_gru<<<dim3(16, 2), 512, 147456, stream>>>(xi, whp0, bhh0, bhh0r, l0);
  k_gemm<<<dim3(400, 12), 256, 0, stream>>>(l0, wcat1, bcat1, xi);
  k_gru<<<dim3(16, 2), 512, 147456, stream>>>(xi, whp1, bhh1, bhh1r, outh);
  k_heads1<<<3200, 256, 0, stream>>>(outh, fc1w, fc1b, fc2w, fc2b, y, y2);
  k_heads2<<<256, 256, 0, stream>>>(y, y2, y3);
}